// Round 10
// baseline (373.103 us; speedup 1.0000x reference)
//
#include <hip/hip_runtime.h>
#include <hip/hip_bf16.h>
#include <hip/hip_fp8.h>
#include <cmath>

// ---------------------------------------------------------------------------
// Round 10: dispatch-count attack (14 -> 11) + quad-gather revert.
//   - fused_conv1: per-block aggregate (64-dim pair-gather) straight into the
//     swizzled LDS A-tile, then MFMA K-loop. ax intermediate deleted.
//   - fused_conv3: aggregate conv2's xw8 (128-dim fp8 pair-gather, +b2) into
//     LDS A-tile + write hcat[128:256] by-product, then GEMM Wt3 -> xw8b.
//   - bucket_hist writes per-block partial hists (no memset, no global
//     atomics); scan_tails column-sums.
//   - aggregates back to R8 pair-gather (2 edges/VMEM, shfl_xor(32) combine).
//   - (R9) linear2 fused into head GEMM epilogue; (R7) fp8 e4m3 xw;
//     bf16 MFMA 128x128/BK32, global_load_lds w16, XOR-swizzled LDS.
// ---------------------------------------------------------------------------

typedef __bf16 bf16;
typedef __bf16 bf16x2 __attribute__((ext_vector_type(2)));
typedef __bf16 bf16x4 __attribute__((ext_vector_type(4)));
typedef __bf16 bf16x8 __attribute__((ext_vector_type(8)));
typedef float  f32x4  __attribute__((ext_vector_type(4)));
typedef unsigned char fp8s;   // e4m3 storage byte

__device__ __forceinline__ void load_lds16(const bf16* g, bf16* l) {
    __builtin_amdgcn_global_load_lds(
        (const __attribute__((address_space(1))) void*)g,
        (__attribute__((address_space(3))) void*)l, 16, 0, 0);
}

__device__ __forceinline__ bf16 convert_out(float v, bf16*) { return (bf16)v; }
__device__ __forceinline__ fp8s convert_out(float v, fp8s*) {
    __hip_fp8_e4m3 q(v); return (fp8s)q.__x;
}

__device__ __forceinline__ float4 fp8x4_to_f4(unsigned int p) {
    __hip_fp8x2_e4m3 lo, hi;
    lo.__x = (__hip_fp8x2_storage_t)(p & 0xffffu);
    hi.__x = (__hip_fp8x2_storage_t)(p >> 16);
    float2 a = (float2)lo, c = (float2)hi;
    return make_float4(a.x, a.y, c.x, c.y);
}

// ---------------- CSR build (bucketed, N <= 65536 path) ----------------

// grid = 256 blocks; block writes its partial hist row (no init, no g-atomics)
__launch_bounds__(256)
__global__ void bucket_hist(const int* __restrict__ dst, int* __restrict__ hist2d, int e) {
    __shared__ int h[256];
    int t = threadIdx.x;
    h[t] = 0;
    __syncthreads();
    for (int i = blockIdx.x * 256 + t; i < e; i += gridDim.x * 256)
        atomicAdd(&h[dst[i] >> 8], 1);
    __syncthreads();
    hist2d[blockIdx.x * 256 + t] = h[t];
}

// column-sum the 256 partial hists, exclusive scan -> tailA + bbase
__launch_bounds__(256)
__global__ void scan_tails(const int* __restrict__ hist2d, int* __restrict__ tailA,
                           int* __restrict__ bbase, int nbuck, int etot) {
    __shared__ int s[256];
    int t = threadIdx.x;
    int v = 0;
    for (int b = 0; b < 256; ++b) v += hist2d[b * 256 + t];
    s[t] = v;
    __syncthreads();
#pragma unroll
    for (int off = 1; off < 256; off <<= 1) {
        int tmp = (t >= off) ? s[t - off] : 0;
        __syncthreads();
        s[t] += tmp;
        __syncthreads();
    }
    int excl = s[t] - v;
    if (t < nbuck) { tailA[t] = excl; bbase[t] = excl; }
    if (t == 0) bbase[nbuck] = etot;
}

__launch_bounds__(256)
__global__ void bin_pairs(const int* __restrict__ src, const int* __restrict__ dst,
                          int* __restrict__ tail, unsigned int* __restrict__ pairs,
                          int e, int nbuck) {
    __shared__ int hist[256], base[256], cur[256];
    int t = threadIdx.x;
    hist[t] = 0; cur[t] = 0;
    __syncthreads();
    int perBlock = (e + gridDim.x - 1) / gridDim.x;
    int lo = blockIdx.x * perBlock;
    int hi = lo + perBlock; if (hi > e) hi = e;
    for (int i = lo + t; i < hi; i += 256)
        atomicAdd(&hist[dst[i] >> 8], 1);
    __syncthreads();
    if (t < nbuck && hist[t] > 0) base[t] = atomicAdd(&tail[t], hist[t]);
    __syncthreads();
    for (int i = lo + t; i < hi; i += 256) {
        int d = dst[i];
        int b = d >> 8;
        int r = atomicAdd(&cur[b], 1);
        pairs[base[b] + r] = (unsigned)src[i] | ((unsigned)(d & 255) << 16);
    }
}

#define FILL_CAP 6144
__launch_bounds__(256)
__global__ void csr_fill_full(const unsigned int* __restrict__ pairs,
                              const int* __restrict__ bbase,
                              int* __restrict__ rp, float* __restrict__ dinv,
                              int* __restrict__ col, int n, int etot) {
    __shared__ int cnt[256];
    __shared__ int ofs[256];
    __shared__ int ss[256];
    __shared__ int win[FILL_CAP];
    int b = blockIdx.x, t = threadIdx.x;
    int nodeBase = b << 8;
    int lo = bbase[b];
    int bcountE = bbase[b + 1] - lo;
    cnt[t] = 0;
    __syncthreads();
    for (int i = t; i < bcountE; i += 256)
        atomicAdd(&cnt[pairs[lo + i] >> 16], 1);
    __syncthreads();
    int myc = cnt[t];
    ss[t] = myc;
    __syncthreads();
#pragma unroll
    for (int off = 1; off < 256; off <<= 1) {
        int tmp = (t >= off) ? ss[t - off] : 0;
        __syncthreads();
        ss[t] += tmp;
        __syncthreads();
    }
    int excl = ss[t] - myc;
    ofs[t] = excl;
    int node = nodeBase + t;
    if (node < n) {
        rp[node]   = lo + excl;
        dinv[node] = rsqrtf((float)(myc + 1));    // +1 self-loop
        if (node == n - 1) rp[n] = etot;
    }
    cnt[t] = 0;
    __syncthreads();
    if (bcountE <= FILL_CAP) {
        for (int i = t; i < bcountE; i += 256) {
            unsigned p = pairs[lo + i];
            int dl = (int)(p >> 16);
            int r = atomicAdd(&cnt[dl], 1);
            win[ofs[dl] + r] = (int)(p & 0xffffu);
        }
        __syncthreads();
        for (int i = t; i < bcountE; i += 256) col[lo + i] = win[i];
    } else {
        for (int i = t; i < bcountE; i += 256) {
            unsigned p = pairs[lo + i];
            int dl = (int)(p >> 16);
            int r = atomicAdd(&cnt[dl], 1);
            col[lo + ofs[dl] + r] = (int)(p & 0xffffu);
        }
    }
}

// -------- fallback CSR build for N > 65536 (not used at this size) --------

__launch_bounds__(256)
__global__ void init_kernel(int* __restrict__ cnt, int* __restrict__ fill, int n) {
    int i = blockIdx.x * 256 + threadIdx.x;
    if (i < n) { cnt[i] = 1; fill[i] = 0; }
}

__launch_bounds__(256)
__global__ void hist_kernel(const int* __restrict__ dst, int* __restrict__ cnt, int e) {
    int i = blockIdx.x * 256 + threadIdx.x;
    if (i < e) atomicAdd(&cnt[dst[i]], 1);
}

__launch_bounds__(256)
__global__ void block_reduce(const int* __restrict__ cnt, int* __restrict__ bsum, int n) {
    __shared__ int s[256];
    int t = threadIdx.x;
    int i = blockIdx.x * 256 + t;
    int v = (i < n) ? cnt[i] - 1 : 0;
    s[t] = v;
    __syncthreads();
#pragma unroll
    for (int off = 128; off > 0; off >>= 1) {
        if (t < off) s[t] += s[t + off];
        __syncthreads();
    }
    if (t == 0) bsum[blockIdx.x] = s[0];
}

__launch_bounds__(256)
__global__ void scan_bsums(int* __restrict__ bsum, int nb) {
    __shared__ int s[256];
    int t = threadIdx.x;
    int v = (t < nb) ? bsum[t] : 0;
    s[t] = v;
    __syncthreads();
#pragma unroll
    for (int off = 1; off < 256; off <<= 1) {
        int tmp = (t >= off) ? s[t - off] : 0;
        __syncthreads();
        s[t] += tmp;
        __syncthreads();
    }
    if (t < nb) bsum[t] = s[t] - v;
}

__launch_bounds__(256)
__global__ void write_rp(const int* __restrict__ cnt, const int* __restrict__ bsum,
                         int* __restrict__ rp, float* __restrict__ dinv, int n, int etot) {
    __shared__ int s[256];
    int t = threadIdx.x;
    int i = blockIdx.x * 256 + t;
    int c = (i < n) ? cnt[i] : 1;
    int v = c - 1;
    s[t] = v;
    __syncthreads();
#pragma unroll
    for (int off = 1; off < 256; off <<= 1) {
        int tmp = (t >= off) ? s[t - off] : 0;
        __syncthreads();
        s[t] += tmp;
        __syncthreads();
    }
    if (i < n) {
        rp[i]   = bsum[blockIdx.x] + s[t] - v;
        dinv[i] = rsqrtf((float)c);
        if (i == n - 1) rp[n] = etot;
    }
}

__launch_bounds__(256)
__global__ void fill_kernel(const int* __restrict__ src, const int* __restrict__ dst,
                            const int* __restrict__ rp, int* __restrict__ fill,
                            int* __restrict__ col, int e) {
    int i = blockIdx.x * 256 + threadIdx.x;
    if (i < e) {
        int d = dst[i];
        int pos = rp[d] + atomicAdd(&fill[d], 1);
        col[pos] = src[i];
    }
}

// ---------------- prep (fused) ----------------
__launch_bounds__(256)
__global__ void prep_all(const float* __restrict__ W1, const float* __restrict__ W2,
                         const float* __restrict__ W3, const float* __restrict__ lW1,
                         const float* __restrict__ x, const float* __restrict__ dinv,
                         bf16* __restrict__ Wt1, bf16* __restrict__ Wt2,
                         bf16* __restrict__ Wt3, bf16* __restrict__ lW1_bf,
                         bf16* __restrict__ xs0, int n64) {
    int i = blockIdx.x * 256 + threadIdx.x;
    if (i < 8192) {
        int k = i >> 7, c = i & 127; Wt1[c * 64 + k] = (bf16)W1[i];
    } else if (i < 24576) {
        int j = i - 8192; int k = j >> 7, c = j & 127; Wt2[c * 128 + k] = (bf16)W2[j];
    } else if (i < 40960) {
        int j = i - 24576; int k = j >> 7, c = j & 127; Wt3[c * 128 + k] = (bf16)W3[j];
    } else if (i < 188416) {
        int j = i - 40960; lW1_bf[j] = (bf16)lW1[j];
    } else {
        int j = i - 188416;
        if (j < n64) xs0[j] = (bf16)(x[j] * dinv[j >> 6]);
    }
}

// ---------------- generic MFMA GEMM ----------------
// EPI: 0 = rowScale, 3 = LOGITS epilogue (relu(v+bias) @ lW2^T -> part)
template<int EPI, typename OutT>
__launch_bounds__(256, 4)
__global__ void mfma_gemm(const bf16* __restrict__ A, int strideA, int K,
                          const bf16* __restrict__ Bt,
                          const float* __restrict__ bias,
                          const float* __restrict__ rowScale,
                          OutT* __restrict__ C, int strideC, int n,
                          const float* __restrict__ lW2 = nullptr,
                          float* __restrict__ part = nullptr) {
    __shared__ bf16 As[128 * 32];
    __shared__ bf16 Bs[128 * 32];
    __shared__ float plds[128 * 2];   // only used by EPI==3
    int t = threadIdx.x;
    int rowBase = blockIdx.x * 128;
    int colBase = blockIdx.y * 128;

    int lane = t & 63;
    int wv   = t >> 6;
    int wr   = wv >> 1, wc = wv & 1;
    int ml   = lane & 15, quad = lane >> 4;

    if (EPI == 3) plds[t] = 0.f;

    f32x4 acc[4][4];
#pragma unroll
    for (int i = 0; i < 4; ++i)
#pragma unroll
        for (int j = 0; j < 4; ++j) acc[i][j] = (f32x4){0.f, 0.f, 0.f, 0.f};

    int srow0 = wv * 32 + (lane >> 2);
    int cchunk = lane & 3;

    for (int kt = 0; kt < K; kt += 32) {
        __syncthreads();
#pragma unroll
        for (int inst = 0; inst < 2; ++inst) {
            int r  = srow0 + inst * 16;
            int gc = (cchunk ^ (r & 3)) * 8;
            int gr = rowBase + r; if (gr >= n) gr = n - 1;
            load_lds16(A + (size_t)gr * strideA + kt + gc,
                       &As[(wv * 128 + inst * 64) * 8]);
            int br = colBase + r;
            load_lds16(Bt + (size_t)br * K + kt + gc,
                       &Bs[(wv * 128 + inst * 64) * 8]);
        }
        __syncthreads();
        bf16x8 af[4], bfv[4];
#pragma unroll
        for (int i = 0; i < 4; ++i) {
            int ra = wr * 64 + i * 16 + ml;
            int rb = wc * 64 + i * 16 + ml;
            af[i]  = *(const bf16x8*)&As[(ra * 4 + (quad ^ (ra & 3))) * 8];
            bfv[i] = *(const bf16x8*)&Bs[(rb * 4 + (quad ^ (rb & 3))) * 8];
        }
#pragma unroll
        for (int i = 0; i < 4; ++i)
#pragma unroll
            for (int j = 0; j < 4; ++j)
                acc[i][j] = __builtin_amdgcn_mfma_f32_16x16x32_bf16(
                    af[i], bfv[j], acc[i][j], 0, 0, 0);
    }

    if (EPI == 3) {
        float b4[4], w0[4], w1[4];
#pragma unroll
        for (int j = 0; j < 4; ++j) {
            int gc = colBase + wc * 64 + j * 16 + ml;
            b4[j] = bias[gc];
            w0[j] = lW2[gc];
            w1[j] = lW2[384 + gc];
        }
#pragma unroll
        for (int i = 0; i < 4; ++i) {
#pragma unroll
            for (int reg = 0; reg < 4; ++reg) {
                float p0 = 0.f, p1 = 0.f;
#pragma unroll
                for (int j = 0; j < 4; ++j) {
                    float v = fmaxf(acc[i][j][reg] + b4[j], 0.f);
                    p0 += v * w0[j];
                    p1 += v * w1[j];
                }
#pragma unroll
                for (int m = 1; m < 16; m <<= 1) {
                    p0 += __shfl_xor(p0, m, 64);
                    p1 += __shfl_xor(p1, m, 64);
                }
                if (ml == 0) {
                    int rl = wr * 64 + i * 16 + quad * 4 + reg;
                    atomicAdd(&plds[rl * 2 + 0], p0);
                    atomicAdd(&plds[rl * 2 + 1], p1);
                }
            }
        }
        __syncthreads();
        int r = t >> 1, c = t & 1;
        int gr = rowBase + r;
        if (gr < n)
            part[((size_t)blockIdx.y * n + gr) * 2 + c] = plds[t];
        return;
    }

#pragma unroll
    for (int i = 0; i < 4; ++i) {
#pragma unroll
        for (int reg = 0; reg < 4; ++reg) {
            int gr = rowBase + wr * 64 + i * 16 + quad * 4 + reg;
            if (gr < n) {
                float sc = rowScale ? rowScale[gr] : 1.f;
#pragma unroll
                for (int j = 0; j < 4; ++j) {
                    int gc = colBase + wc * 64 + j * 16 + ml;
                    C[(size_t)gr * strideC + gc] =
                        convert_out(acc[i][j][reg] * sc, (OutT*)nullptr);
                }
            }
        }
    }
}

// ---------------- fused conv1: aggregate64 -> LDS A-tile -> GEMM ----------------
// A-tile: 128 rows x 64 cols bf16, swizzled (r*8 + (c ^ (r&3)))*8. Each wave
// aggregates 32 nodes (pair-gather: halves handle even/odd edges).
__launch_bounds__(256, 4)
__global__ void fused_conv1(const bf16* __restrict__ xs0, const int* __restrict__ rp,
                            const int* __restrict__ col, const float* __restrict__ dinv,
                            const bf16* __restrict__ Bt,    // Wt1 [128][64]
                            const float* __restrict__ bias, // b1
                            bf16* __restrict__ C, int strideC, int n) {
    __shared__ bf16 As[128 * 64];
    __shared__ bf16 Bs[128 * 32];
    int t = threadIdx.x;
    int rowBase = blockIdx.x * 128;
    int lane = t & 63;
    int wv   = t >> 6;
    int lane32 = lane & 31, half = lane >> 5;

    // phase 1: aggregate
    const bf16* gbase = xs0 + lane32 * 2;
    for (int it = 0; it < 32; ++it) {
        int r = wv * 32 + it;
        int v = rowBase + r; if (v >= n) v = n - 1;
        float di = dinv[v];
        int b = rp[v], e = rp[v + 1];
        int deg = e - b;
        float ax = 0.f, ay = 0.f;
        for (int j0 = 0; j0 < deg; j0 += 64) {
            int rem = deg - j0; if (rem > 64) rem = 64;
            int cj = (lane < rem) ? col[b + j0 + lane] : 0;
            int jj = 0;
            for (; jj + 8 <= rem; jj += 8) {
                int s0 = __shfl(cj, jj + 0 + half, 64);
                int s1 = __shfl(cj, jj + 2 + half, 64);
                int s2 = __shfl(cj, jj + 4 + half, 64);
                int s3 = __shfl(cj, jj + 6 + half, 64);
                bf16x2 m0 = *(const bf16x2*)(gbase + (size_t)s0 * 64);
                bf16x2 m1 = *(const bf16x2*)(gbase + (size_t)s1 * 64);
                bf16x2 m2 = *(const bf16x2*)(gbase + (size_t)s2 * 64);
                bf16x2 m3 = *(const bf16x2*)(gbase + (size_t)s3 * 64);
                ax += ((float)m0[0] + (float)m1[0]) + ((float)m2[0] + (float)m3[0]);
                ay += ((float)m0[1] + (float)m1[1]) + ((float)m2[1] + (float)m3[1]);
            }
            for (; jj + 2 <= rem; jj += 2) {
                int s = __shfl(cj, jj + half, 64);
                bf16x2 m = *(const bf16x2*)(gbase + (size_t)s * 64);
                ax += (float)m[0]; ay += (float)m[1];
            }
            if (jj < rem) {
                int s = __shfl(cj, jj, 64);
                bf16x2 m = *(const bf16x2*)(gbase + (size_t)s * 64);
                if (half == 0) { ax += (float)m[0]; ay += (float)m[1]; }
            }
        }
        ax += __shfl_xor(ax, 32, 64);
        ay += __shfl_xor(ay, 32, 64);
        if (half == 0) {
            bf16x2 mv = *(const bf16x2*)(gbase + (size_t)v * 64);
            bf16x2 o;
            o[0] = (bf16)(di * (ax + (float)mv[0]));
            o[1] = (bf16)(di * (ay + (float)mv[1]));
            int c0 = lane32 * 2;
            int lidx = (r * 8 + ((c0 >> 3) ^ (r & 3))) * 8 + (c0 & 7);
            *(bf16x2*)&As[lidx] = o;
        }
    }

    // phase 2: GEMM (K=64)
    int wr = wv >> 1, wc = wv & 1;
    int ml = lane & 15, quad = lane >> 4;
    f32x4 acc[4][4];
#pragma unroll
    for (int i = 0; i < 4; ++i)
#pragma unroll
        for (int j = 0; j < 4; ++j) acc[i][j] = (f32x4){0.f, 0.f, 0.f, 0.f};
    int srow0 = wv * 32 + (lane >> 2);
    int cchunk = lane & 3;
    for (int kt = 0; kt < 64; kt += 32) {
        __syncthreads();
#pragma unroll
        for (int inst = 0; inst < 2; ++inst) {
            int r = srow0 + inst * 16;
            int gc = (cchunk ^ (r & 3)) * 8;
            load_lds16(Bt + (size_t)r * 64 + kt + gc,
                       &Bs[(wv * 128 + inst * 64) * 8]);
        }
        __syncthreads();
        bf16x8 af[4], bfv[4];
#pragma unroll
        for (int i = 0; i < 4; ++i) {
            int ra = wr * 64 + i * 16 + ml;
            int rb = wc * 64 + i * 16 + ml;
            af[i]  = *(const bf16x8*)&As[(ra * 8 + (((kt >> 3) + quad) ^ (ra & 3))) * 8];
            bfv[i] = *(const bf16x8*)&Bs[(rb * 4 + (quad ^ (rb & 3))) * 8];
        }
#pragma unroll
        for (int i = 0; i < 4; ++i)
#pragma unroll
            for (int j = 0; j < 4; ++j)
                acc[i][j] = __builtin_amdgcn_mfma_f32_16x16x32_bf16(
                    af[i], bfv[j], acc[i][j], 0, 0, 0);
    }
#pragma unroll
    for (int i = 0; i < 4; ++i) {
#pragma unroll
        for (int reg = 0; reg < 4; ++reg) {
            int gr = rowBase + wr * 64 + i * 16 + quad * 4 + reg;
            if (gr < n) {
#pragma unroll
                for (int j = 0; j < 4; ++j) {
                    int gc = wc * 64 + j * 16 + ml;
                    C[(size_t)gr * strideC + gc] = (bf16)(acc[i][j][reg] + bias[gc]);
                }
            }
        }
    }
}

// ------- fused conv3: aggregate_fp8(xw8)+b2 -> LDS A-tile (+hcat write) -> GEMM -------
// A-tile: 128 rows x 128 cols bf16 (32 KB), swizzled (r*16 + (c ^ (r&3)))*8.
__launch_bounds__(256, 4)
__global__ void fused_conv3(const fp8s* __restrict__ xw8, const int* __restrict__ rp,
                            const int* __restrict__ col, const float* __restrict__ dinv,
                            const float* __restrict__ aggBias,  // b2
                            const bf16* __restrict__ Bt,        // Wt3 [128][128]
                            bf16* __restrict__ hcatOut,         // hcat+128, stride 384
                            fp8s* __restrict__ C, int n) {      // xw8b, stride 128
    __shared__ bf16 As[128 * 128];
    __shared__ bf16 Bs[128 * 32];
    int t = threadIdx.x;
    int rowBase = blockIdx.x * 128;
    int lane = t & 63;
    int wv   = t >> 6;
    int lane32 = lane & 31, half = lane >> 5;

    // phase 1: aggregate (fp8 pair-gather, 4 cols/lane)
    const fp8s* gbase = xw8 + lane32 * 4;
    for (int it = 0; it < 32; ++it) {
        int r = wv * 32 + it;
        int v = rowBase + r; if (v >= n) v = n - 1;
        float di = dinv[v];
        int b = rp[v], e = rp[v + 1];
        int deg = e - b;
        float a0 = 0.f, a1 = 0.f, a2 = 0.f, a3 = 0.f;
        for (int j0 = 0; j0 < deg; j0 += 64) {
            int rem = deg - j0; if (rem > 64) rem = 64;
            int cj = (lane < rem) ? col[b + j0 + lane] : 0;
            int jj = 0;
            for (; jj + 8 <= rem; jj += 8) {
                int s0 = __shfl(cj, jj + 0 + half, 64);
                int s1 = __shfl(cj, jj + 2 + half, 64);
                int s2 = __shfl(cj, jj + 4 + half, 64);
                int s3 = __shfl(cj, jj + 6 + half, 64);
                float4 f0 = fp8x4_to_f4(*(const unsigned*)(gbase + (size_t)s0 * 128));
                float4 f1 = fp8x4_to_f4(*(const unsigned*)(gbase + (size_t)s1 * 128));
                float4 f2 = fp8x4_to_f4(*(const unsigned*)(gbase + (size_t)s2 * 128));
                float4 f3 = fp8x4_to_f4(*(const unsigned*)(gbase + (size_t)s3 * 128));
                a0 += (f0.x + f1.x) + (f2.x + f3.x);
                a1 += (f0.y + f1.y) + (f2.y + f3.y);
                a2 += (f0.z + f1.z) + (f2.z + f3.z);
                a3 += (f0.w + f1.w) + (f2.w + f3.w);
            }
            for (; jj + 2 <= rem; jj += 2) {
                int s = __shfl(cj, jj + half, 64);
                float4 f = fp8x4_to_f4(*(const unsigned*)(gbase + (size_t)s * 128));
                a0 += f.x; a1 += f.y; a2 += f.z; a3 += f.w;
            }
            if (jj < rem) {
                int s = __shfl(cj, jj, 64);
                float4 f = fp8x4_to_f4(*(const unsigned*)(gbase + (size_t)s * 128));
                if (half == 0) { a0 += f.x; a1 += f.y; a2 += f.z; a3 += f.w; }
            }
        }
        a0 += __shfl_xor(a0, 32, 64);
        a1 += __shfl_xor(a1, 32, 64);
        a2 += __shfl_xor(a2, 32, 64);
        a3 += __shfl_xor(a3, 32, 64);
        if (half == 0) {
            float4 fv = fp8x4_to_f4(*(const unsigned*)(gbase + (size_t)v * 128));
            int c0 = lane32 * 4;
            float4 bb = *(const float4*)(aggBias + c0);
            bf16x4 o;
            o[0] = (bf16)(di * (a0 + fv.x) + bb.x);
            o[1] = (bf16)(di * (a1 + fv.y) + bb.y);
            o[2] = (bf16)(di * (a2 + fv.z) + bb.z);
            o[3] = (bf16)(di * (a3 + fv.w) + bb.w);
            int lidx = (r * 16 + ((c0 >> 3) ^ (r & 3))) * 8 + (c0 & 7);
            *(bf16x4*)&As[lidx] = o;
            *(bf16x4*)(hcatOut + (size_t)v * 384 + c0) = o;   // h2 by-product
        }
    }

    // phase 2: GEMM (K=128)
    int wr = wv >> 1, wc = wv & 1;
    int ml = lane & 15, quad = lane >> 4;
    f32x4 acc[4][4];
#pragma unroll
    for (int i = 0; i < 4; ++i)
#pragma unroll
        for (int j = 0; j < 4; ++j) acc[i][j] = (f32x4){0.f, 0.f, 0.f, 0.f};
    int srow0 = wv * 32 + (lane >> 2);
    int cchunk = lane & 3;
    for (int kt = 0; kt < 128; kt += 32) {
        __syncthreads();
#pragma unroll
        for (int inst = 0; inst < 2; ++inst) {
            int r = srow0 + inst * 16;
            int gc = (cchunk ^ (r & 3)) * 8;
            load_lds16(Bt + (size_t)r * 128 + kt + gc,
                       &Bs[(wv * 128 + inst * 64) * 8]);
        }
        __syncthreads();
        bf16x8 af[4], bfv[4];
#pragma unroll
        for (int i = 0; i < 4; ++i) {
            int ra = wr * 64 + i * 16 + ml;
            int rb = wc * 64 + i * 16 + ml;
            af[i]  = *(const bf16x8*)&As[(ra * 16 + (((kt >> 3) + quad) ^ (ra & 3))) * 8];
            bfv[i] = *(const bf16x8*)&Bs[(rb * 4 + (quad ^ (rb & 3))) * 8];
        }
#pragma unroll
        for (int i = 0; i < 4; ++i)
#pragma unroll
            for (int j = 0; j < 4; ++j)
                acc[i][j] = __builtin_amdgcn_mfma_f32_16x16x32_bf16(
                    af[i], bfv[j], acc[i][j], 0, 0, 0);
    }
#pragma unroll
    for (int i = 0; i < 4; ++i) {
#pragma unroll
        for (int reg = 0; reg < 4; ++reg) {
            int gr = rowBase + wr * 64 + i * 16 + quad * 4 + reg;
            if (gr < n) {
                float sc = dinv[gr];
#pragma unroll
                for (int j = 0; j < 4; ++j) {
                    int gc = wc * 64 + j * 16 + ml;
                    __hip_fp8_e4m3 q(acc[i][j][reg] * sc);
                    C[(size_t)gr * 128 + gc] = (fp8s)q.__x;
                }
            }
        }
    }
}

// ---------------- standalone aggregate (fp8, pair-gather, R8) ----------------
__launch_bounds__(256)
__global__ void aggregate_fp8(const fp8s* __restrict__ xs, const int* __restrict__ rp,
                              const int* __restrict__ col, const float* __restrict__ dinv,
                              const float* __restrict__ bias, bf16* __restrict__ out,
                              int outStride, int n) {
    int gid  = blockIdx.x * 256 + threadIdx.x;
    int v    = gid >> 6;
    int lane = gid & 63;
    if (v >= n) return;
    int lane32 = lane & 31;
    int half   = lane >> 5;
    float di = dinv[v];
    int b = rp[v], e = rp[v + 1];
    int deg = e - b;
    const fp8s* base = xs + lane32 * 4;
    float a0 = 0.f, a1 = 0.f, a2 = 0.f, a3 = 0.f;
    for (int j0 = 0; j0 < deg; j0 += 64) {
        int rem = deg - j0; if (rem > 64) rem = 64;
        int cj = (lane < rem) ? col[b + j0 + lane] : 0;
        int jj = 0;
        for (; jj + 8 <= rem; jj += 8) {
            int s0 = __shfl(cj, jj + 0 + half, 64);
            int s1 = __shfl(cj, jj + 2 + half, 64);
            int s2 = __shfl(cj, jj + 4 + half, 64);
            int s3 = __shfl(cj, jj + 6 + half, 64);
            float4 f0 = fp8x4_to_f4(*(const unsigned*)(base + (size_t)s0 * 128));
            float4 f1 = fp8x4_to_f4(*(const unsigned*)(base + (size_t)s1 * 128));
            float4 f2 = fp8x4_to_f4(*(const unsigned*)(base + (size_t)s2 * 128));
            float4 f3 = fp8x4_to_f4(*(const unsigned*)(base + (size_t)s3 * 128));
            a0 += (f0.x + f1.x) + (f2.x + f3.x);
            a1 += (f0.y + f1.y) + (f2.y + f3.y);
            a2 += (f0.z + f1.z) + (f2.z + f3.z);
            a3 += (f0.w + f1.w) + (f2.w + f3.w);
        }
        for (; jj + 2 <= rem; jj += 2) {
            int s = __shfl(cj, jj + half, 64);
            float4 f = fp8x4_to_f4(*(const unsigned*)(base + (size_t)s * 128));
            a0 += f.x; a1 += f.y; a2 += f.z; a3 += f.w;
        }
        if (jj < rem) {
            int s = __shfl(cj, jj, 64);
            float4 f = fp8x4_to_f4(*(const unsigned*)(base + (size_t)s * 128));
            if (half == 0) { a0 += f.x; a1 += f.y; a2 += f.z; a3 += f.w; }
        }
    }
    a0 += __shfl_xor(a0, 32, 64);
    a1 += __shfl_xor(a1, 32, 64);
    a2 += __shfl_xor(a2, 32, 64);
    a3 += __shfl_xor(a3, 32, 64);
    if (half == 0) {
        float4 fv = fp8x4_to_f4(*(const unsigned*)(base + (size_t)v * 128));
        float4 bb = *(const float4*)(bias + lane32 * 4);
        bf16x4 o;
        o[0] = (bf16)(di * (a0 + fv.x) + bb.x);
        o[1] = (bf16)(di * (a1 + fv.y) + bb.y);
        o[2] = (bf16)(di * (a2 + fv.z) + bb.z);
        o[3] = (bf16)(di * (a3 + fv.w) + bb.w);
        *(bf16x4*)(out + (size_t)v * outStride + lane32 * 4) = o;
    }
}

// ---------------- softmax final ----------------
__launch_bounds__(256)
__global__ void softmax_final(const float* __restrict__ part, const float* __restrict__ lb2,
                              float* __restrict__ out, int n) {
    int i = blockIdx.x * 256 + threadIdx.x;
    if (i >= n) return;
    size_t seg = (size_t)n * 2;
    float2 p0 = *(const float2*)(part + (size_t)i * 2);
    float2 p1 = *(const float2*)(part + seg + (size_t)i * 2);
    float2 p2 = *(const float2*)(part + 2 * seg + (size_t)i * 2);
    float l0 = p0.x + p1.x + p2.x + lb2[0];
    float l1 = p0.y + p1.y + p2.y + lb2[1];
    *(float2*)(out + (size_t)i * 2) = make_float2(l0, l1);
    float m  = fmaxf(l0, l1);
    float e0 = expf(l0 - m), e1 = expf(l1 - m);
    float inv = 1.f / (e0 + e1);
    *(float2*)(out + seg + (size_t)i * 2) = make_float2(e0 * inv, e1 * inv);
}

extern "C" void kernel_launch(void* const* d_in, const int* in_sizes, int n_in,
                              void* d_out, int out_size, void* d_ws, size_t ws_size,
                              hipStream_t stream) {
    const float* x   = (const float*)d_in[0];
    const int*   ei  = (const int*)d_in[1];
    const float* W1  = (const float*)d_in[2];
    const float* b1  = (const float*)d_in[3];
    const float* W2  = (const float*)d_in[4];
    const float* b2  = (const float*)d_in[5];
    const float* W3  = (const float*)d_in[6];
    const float* b3  = (const float*)d_in[7];
    const float* lW1 = (const float*)d_in[8];
    const float* lb1 = (const float*)d_in[9];
    const float* lW2 = (const float*)d_in[10];
    const float* lb2 = (const float*)d_in[11];
    float* out = (float*)d_out;

    int N = in_sizes[0] / 64;
    int E = in_sizes[1] / 2;
    const int* src = ei;
    const int* dst = ei + E;

    char* ws = (char*)d_ws;
    size_t off = 0;
    auto take = [&](size_t bytes) -> char* {
        char* p = ws + off;
        off += (bytes + 255) & ~(size_t)255;
        return p;
    };
    int nBlk  = (N + 255) / 256;
    int nbuck = nBlk;
    int*   cnt    = (int*)take((size_t)N * 4);         // fallback only
    int*   fill   = (int*)take((size_t)N * 4);         // fallback only
    int*   rp     = (int*)take((size_t)(N + 1) * 4);
    float* dinv   = (float*)take((size_t)N * 4);
    int*   bsum   = (int*)take((size_t)nBlk * 4);      // fallback only
    int*   hist2d = (int*)take((size_t)256 * 256 * 4);
    int*   tailA  = (int*)take((size_t)nbuck * 4);
    int*   bbase  = (int*)take((size_t)(nbuck + 1) * 4);
    int*   col    = (int*)take((size_t)E * 4);
    unsigned int* pairs = (unsigned int*)take((size_t)E * 4);
    bf16*  xs0    = (bf16*)take((size_t)N * 64 * 2);
    bf16*  Wt1    = (bf16*)take((size_t)64 * 128 * 2);
    bf16*  Wt2    = (bf16*)take((size_t)128 * 128 * 2);
    bf16*  Wt3    = (bf16*)take((size_t)128 * 128 * 2);
    bf16*  lW1_bf = (bf16*)take((size_t)384 * 384 * 2);
    fp8s*  xw8a   = (fp8s*)take((size_t)N * 128);
    fp8s*  xw8b   = (fp8s*)take((size_t)N * 128);
    bf16*  hcat   = (bf16*)take((size_t)N * 384 * 2);
    float* part   = (float*)take((size_t)N * 2 * 3 * 4);

    // CSR build (4 dispatches, no memset, no global-atomic hist)
    if (nbuck <= 256 && N <= 65536) {
        bucket_hist<<<256, 256, 0, stream>>>(dst, hist2d, E);
        scan_tails<<<1, 256, 0, stream>>>(hist2d, tailA, bbase, nbuck, E);
        bin_pairs<<<nbuck, 256, 0, stream>>>(src, dst, tailA, pairs, E, nbuck);
        csr_fill_full<<<nbuck, 256, 0, stream>>>(pairs, bbase, rp, dinv, col, N, E);
    } else {
        init_kernel<<<nBlk, 256, 0, stream>>>(cnt, fill, N);
        hist_kernel<<<(E + 255) / 256, 256, 0, stream>>>(dst, cnt, E);
        block_reduce<<<nBlk, 256, 0, stream>>>(cnt, bsum, N);
        scan_bsums<<<1, 256, 0, stream>>>(bsum, nBlk);
        write_rp<<<nBlk, 256, 0, stream>>>(cnt, bsum, rp, dinv, N, E);
        fill_kernel<<<(E + 255) / 256, 256, 0, stream>>>(src, dst, rp, fill, col, E);
    }

    // prep (weights + dinv-scaled x cast, one launch)
    int prepElems = 188416 + N * 64;
    prep_all<<<(prepElems + 255) / 256, 256, 0, stream>>>(
        W1, W2, W3, lW1, x, dinv, Wt1, Wt2, Wt3, lW1_bf, xs0, N * 64);

    int gemmBlocks = (N + 127) / 128;
    int aggBlocks  = (N + 3) / 4;

    // conv1 fused: aggregate(xs0) -> GEMM Wt1 (+b1) -> hcat[:,0:128)
    fused_conv1<<<gemmBlocks, 256, 0, stream>>>(
        xs0, rp, col, dinv, Wt1, b1, hcat + 0, 384, N);
    // conv2 GEMM: hcat[0:128] @ Wt2 -> xw8a (rows pre-scaled by dinv)
    mfma_gemm<0, fp8s><<<dim3(gemmBlocks, 1), 256, 0, stream>>>(
        hcat + 0, 384, 128, Wt2, nullptr, dinv, xw8a, 128, N);
    // conv3 fused: aggregate(xw8a)+b2 -> hcat[:,128:256) + GEMM Wt3 -> xw8b
    fused_conv3<<<gemmBlocks, 256, 0, stream>>>(
        xw8a, rp, col, dinv, b2, Wt3, hcat + 128, xw8b, N);
    // conv3 aggregate: xw8b -> hcat[:,256:384) (+b3)
    aggregate_fp8<<<aggBlocks, 256, 0, stream>>>(xw8b, rp, col, dinv, b3, hcat + 256, 384, N);

    // MLP head: linear1+relu+linear2 fused (partial logits per y), then softmax
    mfma_gemm<3, bf16><<<dim3(gemmBlocks, 3), 256, 0, stream>>>(
        hcat, 384, 384, lW1_bf, lb1, nullptr, (bf16*)nullptr, 0, N, lW2, part);
    softmax_final<<<(N + 255) / 256, 256, 0, stream>>>(part, lb2, out, N);
}

// Round 11
// 273.568 us; speedup vs baseline: 1.3638x; 1.3638x over previous
//
#include <hip/hip_runtime.h>
#include <hip/hip_bf16.h>
#include <hip/hip_fp8.h>
#include <cmath>

// ---------------------------------------------------------------------------
// Round 11: recombination of proven-best pieces (R10's fusion REVERTED —
// it serialized the latency-bound gather, 8x TLP loss, 94us fused_conv3):
//   - R8 pair-gather standalone aggregates (2 edges/VMEM, shfl_xor(32)).
//   - R9 head fusion: linear1+relu+linear2 in one GEMM epilogue -> part,
//     softmax_final. hrel (38 MB RW) never materialized.
//   - R10 memset-free bucket_hist (per-block partial hists + column-sum).
//   - (R7) fp8 e4m3 xw; bf16 MFMA 128x128/BK32, global_load_lds w16,
//     XOR-swizzled LDS.
// ---------------------------------------------------------------------------

typedef __bf16 bf16;
typedef __bf16 bf16x2 __attribute__((ext_vector_type(2)));
typedef __bf16 bf16x4 __attribute__((ext_vector_type(4)));
typedef __bf16 bf16x8 __attribute__((ext_vector_type(8)));
typedef float  f32x4  __attribute__((ext_vector_type(4)));
typedef unsigned char fp8s;   // e4m3 storage byte

__device__ __forceinline__ void load_lds16(const bf16* g, bf16* l) {
    __builtin_amdgcn_global_load_lds(
        (const __attribute__((address_space(1))) void*)g,
        (__attribute__((address_space(3))) void*)l, 16, 0, 0);
}

__device__ __forceinline__ bf16 convert_out(float v, bf16*) { return (bf16)v; }
__device__ __forceinline__ fp8s convert_out(float v, fp8s*) {
    __hip_fp8_e4m3 q(v); return (fp8s)q.__x;
}

__device__ __forceinline__ float4 fp8x4_to_f4(unsigned int p) {
    __hip_fp8x2_e4m3 lo, hi;
    lo.__x = (__hip_fp8x2_storage_t)(p & 0xffffu);
    hi.__x = (__hip_fp8x2_storage_t)(p >> 16);
    float2 a = (float2)lo, c = (float2)hi;
    return make_float4(a.x, a.y, c.x, c.y);
}

// ---------------- CSR build (bucketed, N <= 65536 path) ----------------

// grid = 256 blocks; block writes its partial hist row (no init, no g-atomics)
__launch_bounds__(256)
__global__ void bucket_hist(const int* __restrict__ dst, int* __restrict__ hist2d, int e) {
    __shared__ int h[256];
    int t = threadIdx.x;
    h[t] = 0;
    __syncthreads();
    for (int i = blockIdx.x * 256 + t; i < e; i += gridDim.x * 256)
        atomicAdd(&h[dst[i] >> 8], 1);
    __syncthreads();
    hist2d[blockIdx.x * 256 + t] = h[t];
}

// column-sum the 256 partial hists, exclusive scan -> tailA + bbase
__launch_bounds__(256)
__global__ void scan_tails(const int* __restrict__ hist2d, int* __restrict__ tailA,
                           int* __restrict__ bbase, int nbuck, int etot) {
    __shared__ int s[256];
    int t = threadIdx.x;
    int v = 0;
    for (int b = 0; b < 256; ++b) v += hist2d[b * 256 + t];
    s[t] = v;
    __syncthreads();
#pragma unroll
    for (int off = 1; off < 256; off <<= 1) {
        int tmp = (t >= off) ? s[t - off] : 0;
        __syncthreads();
        s[t] += tmp;
        __syncthreads();
    }
    int excl = s[t] - v;
    if (t < nbuck) { tailA[t] = excl; bbase[t] = excl; }
    if (t == 0) bbase[nbuck] = etot;
}

__launch_bounds__(256)
__global__ void bin_pairs(const int* __restrict__ src, const int* __restrict__ dst,
                          int* __restrict__ tail, unsigned int* __restrict__ pairs,
                          int e, int nbuck) {
    __shared__ int hist[256], base[256], cur[256];
    int t = threadIdx.x;
    hist[t] = 0; cur[t] = 0;
    __syncthreads();
    int perBlock = (e + gridDim.x - 1) / gridDim.x;
    int lo = blockIdx.x * perBlock;
    int hi = lo + perBlock; if (hi > e) hi = e;
    for (int i = lo + t; i < hi; i += 256)
        atomicAdd(&hist[dst[i] >> 8], 1);
    __syncthreads();
    if (t < nbuck && hist[t] > 0) base[t] = atomicAdd(&tail[t], hist[t]);
    __syncthreads();
    for (int i = lo + t; i < hi; i += 256) {
        int d = dst[i];
        int b = d >> 8;
        int r = atomicAdd(&cur[b], 1);
        pairs[base[b] + r] = (unsigned)src[i] | ((unsigned)(d & 255) << 16);
    }
}

#define FILL_CAP 6144
__launch_bounds__(256)
__global__ void csr_fill_full(const unsigned int* __restrict__ pairs,
                              const int* __restrict__ bbase,
                              int* __restrict__ rp, float* __restrict__ dinv,
                              int* __restrict__ col, int n, int etot) {
    __shared__ int cnt[256];
    __shared__ int ofs[256];
    __shared__ int ss[256];
    __shared__ int win[FILL_CAP];
    int b = blockIdx.x, t = threadIdx.x;
    int nodeBase = b << 8;
    int lo = bbase[b];
    int bcountE = bbase[b + 1] - lo;
    cnt[t] = 0;
    __syncthreads();
    for (int i = t; i < bcountE; i += 256)
        atomicAdd(&cnt[pairs[lo + i] >> 16], 1);
    __syncthreads();
    int myc = cnt[t];
    ss[t] = myc;
    __syncthreads();
#pragma unroll
    for (int off = 1; off < 256; off <<= 1) {
        int tmp = (t >= off) ? ss[t - off] : 0;
        __syncthreads();
        ss[t] += tmp;
        __syncthreads();
    }
    int excl = ss[t] - myc;
    ofs[t] = excl;
    int node = nodeBase + t;
    if (node < n) {
        rp[node]   = lo + excl;
        dinv[node] = rsqrtf((float)(myc + 1));    // +1 self-loop
        if (node == n - 1) rp[n] = etot;
    }
    cnt[t] = 0;
    __syncthreads();
    if (bcountE <= FILL_CAP) {
        for (int i = t; i < bcountE; i += 256) {
            unsigned p = pairs[lo + i];
            int dl = (int)(p >> 16);
            int r = atomicAdd(&cnt[dl], 1);
            win[ofs[dl] + r] = (int)(p & 0xffffu);
        }
        __syncthreads();
        for (int i = t; i < bcountE; i += 256) col[lo + i] = win[i];
    } else {
        for (int i = t; i < bcountE; i += 256) {
            unsigned p = pairs[lo + i];
            int dl = (int)(p >> 16);
            int r = atomicAdd(&cnt[dl], 1);
            col[lo + ofs[dl] + r] = (int)(p & 0xffffu);
        }
    }
}

// -------- fallback CSR build for N > 65536 (not used at this size) --------

__launch_bounds__(256)
__global__ void init_kernel(int* __restrict__ cnt, int* __restrict__ fill, int n) {
    int i = blockIdx.x * 256 + threadIdx.x;
    if (i < n) { cnt[i] = 1; fill[i] = 0; }
}

__launch_bounds__(256)
__global__ void hist_kernel(const int* __restrict__ dst, int* __restrict__ cnt, int e) {
    int i = blockIdx.x * 256 + threadIdx.x;
    if (i < e) atomicAdd(&cnt[dst[i]], 1);
}

__launch_bounds__(256)
__global__ void block_reduce(const int* __restrict__ cnt, int* __restrict__ bsum, int n) {
    __shared__ int s[256];
    int t = threadIdx.x;
    int i = blockIdx.x * 256 + t;
    int v = (i < n) ? cnt[i] - 1 : 0;
    s[t] = v;
    __syncthreads();
#pragma unroll
    for (int off = 128; off > 0; off >>= 1) {
        if (t < off) s[t] += s[t + off];
        __syncthreads();
    }
    if (t == 0) bsum[blockIdx.x] = s[0];
}

__launch_bounds__(256)
__global__ void scan_bsums(int* __restrict__ bsum, int nb) {
    __shared__ int s[256];
    int t = threadIdx.x;
    int v = (t < nb) ? bsum[t] : 0;
    s[t] = v;
    __syncthreads();
#pragma unroll
    for (int off = 1; off < 256; off <<= 1) {
        int tmp = (t >= off) ? s[t - off] : 0;
        __syncthreads();
        s[t] += tmp;
        __syncthreads();
    }
    if (t < nb) bsum[t] = s[t] - v;
}

__launch_bounds__(256)
__global__ void write_rp(const int* __restrict__ cnt, const int* __restrict__ bsum,
                         int* __restrict__ rp, float* __restrict__ dinv, int n, int etot) {
    __shared__ int s[256];
    int t = threadIdx.x;
    int i = blockIdx.x * 256 + t;
    int c = (i < n) ? cnt[i] : 1;
    int v = c - 1;
    s[t] = v;
    __syncthreads();
#pragma unroll
    for (int off = 1; off < 256; off <<= 1) {
        int tmp = (t >= off) ? s[t - off] : 0;
        __syncthreads();
        s[t] += tmp;
        __syncthreads();
    }
    if (i < n) {
        rp[i]   = bsum[blockIdx.x] + s[t] - v;
        dinv[i] = rsqrtf((float)c);
        if (i == n - 1) rp[n] = etot;
    }
}

__launch_bounds__(256)
__global__ void fill_kernel(const int* __restrict__ src, const int* __restrict__ dst,
                            const int* __restrict__ rp, int* __restrict__ fill,
                            int* __restrict__ col, int e) {
    int i = blockIdx.x * 256 + threadIdx.x;
    if (i < e) {
        int d = dst[i];
        int pos = rp[d] + atomicAdd(&fill[d], 1);
        col[pos] = src[i];
    }
}

// ---------------- prep (fused) ----------------
__launch_bounds__(256)
__global__ void prep_all(const float* __restrict__ W1, const float* __restrict__ W2,
                         const float* __restrict__ W3, const float* __restrict__ lW1,
                         const float* __restrict__ x, const float* __restrict__ dinv,
                         bf16* __restrict__ Wt1, bf16* __restrict__ Wt2,
                         bf16* __restrict__ Wt3, bf16* __restrict__ lW1_bf,
                         bf16* __restrict__ xs0, int n64) {
    int i = blockIdx.x * 256 + threadIdx.x;
    if (i < 8192) {
        int k = i >> 7, c = i & 127; Wt1[c * 64 + k] = (bf16)W1[i];
    } else if (i < 24576) {
        int j = i - 8192; int k = j >> 7, c = j & 127; Wt2[c * 128 + k] = (bf16)W2[j];
    } else if (i < 40960) {
        int j = i - 24576; int k = j >> 7, c = j & 127; Wt3[c * 128 + k] = (bf16)W3[j];
    } else if (i < 188416) {
        int j = i - 40960; lW1_bf[j] = (bf16)lW1[j];
    } else {
        int j = i - 188416;
        if (j < n64) xs0[j] = (bf16)(x[j] * dinv[j >> 6]);
    }
}

// ---------------- MFMA GEMM ----------------
// EPI: 0 = rowScale only, 1 = +bias, 3 = LOGITS (relu(v+bias) @ lW2^T -> part)
template<int EPI, typename OutT>
__launch_bounds__(256, 4)
__global__ void mfma_gemm(const bf16* __restrict__ A, int strideA, int K,
                          const bf16* __restrict__ Bt,
                          const float* __restrict__ bias,
                          const float* __restrict__ rowScale,
                          OutT* __restrict__ C, int strideC, int n,
                          const float* __restrict__ lW2 = nullptr,
                          float* __restrict__ part = nullptr) {
    __shared__ bf16 As[128 * 32];
    __shared__ bf16 Bs[128 * 32];
    __shared__ float plds[128 * 2];   // only used by EPI==3
    int t = threadIdx.x;
    int rowBase = blockIdx.x * 128;
    int colBase = blockIdx.y * 128;

    int lane = t & 63;
    int wv   = t >> 6;
    int wr   = wv >> 1, wc = wv & 1;
    int ml   = lane & 15, quad = lane >> 4;

    if (EPI == 3) plds[t] = 0.f;

    f32x4 acc[4][4];
#pragma unroll
    for (int i = 0; i < 4; ++i)
#pragma unroll
        for (int j = 0; j < 4; ++j) acc[i][j] = (f32x4){0.f, 0.f, 0.f, 0.f};

    int srow0 = wv * 32 + (lane >> 2);
    int cchunk = lane & 3;

    for (int kt = 0; kt < K; kt += 32) {
        __syncthreads();
#pragma unroll
        for (int inst = 0; inst < 2; ++inst) {
            int r  = srow0 + inst * 16;
            int gc = (cchunk ^ (r & 3)) * 8;
            int gr = rowBase + r; if (gr >= n) gr = n - 1;
            load_lds16(A + (size_t)gr * strideA + kt + gc,
                       &As[(wv * 128 + inst * 64) * 8]);
            int br = colBase + r;
            load_lds16(Bt + (size_t)br * K + kt + gc,
                       &Bs[(wv * 128 + inst * 64) * 8]);
        }
        __syncthreads();
        bf16x8 af[4], bfv[4];
#pragma unroll
        for (int i = 0; i < 4; ++i) {
            int ra = wr * 64 + i * 16 + ml;
            int rb = wc * 64 + i * 16 + ml;
            af[i]  = *(const bf16x8*)&As[(ra * 4 + (quad ^ (ra & 3))) * 8];
            bfv[i] = *(const bf16x8*)&Bs[(rb * 4 + (quad ^ (rb & 3))) * 8];
        }
#pragma unroll
        for (int i = 0; i < 4; ++i)
#pragma unroll
            for (int j = 0; j < 4; ++j)
                acc[i][j] = __builtin_amdgcn_mfma_f32_16x16x32_bf16(
                    af[i], bfv[j], acc[i][j], 0, 0, 0);
    }

    if (EPI == 3) {
        float b4[4], w0[4], w1[4];
#pragma unroll
        for (int j = 0; j < 4; ++j) {
            int gc = colBase + wc * 64 + j * 16 + ml;
            b4[j] = bias[gc];
            w0[j] = lW2[gc];
            w1[j] = lW2[384 + gc];
        }
#pragma unroll
        for (int i = 0; i < 4; ++i) {
#pragma unroll
            for (int reg = 0; reg < 4; ++reg) {
                float p0 = 0.f, p1 = 0.f;
#pragma unroll
                for (int j = 0; j < 4; ++j) {
                    float v = fmaxf(acc[i][j][reg] + b4[j], 0.f);
                    p0 += v * w0[j];
                    p1 += v * w1[j];
                }
#pragma unroll
                for (int m = 1; m < 16; m <<= 1) {
                    p0 += __shfl_xor(p0, m, 64);
                    p1 += __shfl_xor(p1, m, 64);
                }
                if (ml == 0) {
                    int rl = wr * 64 + i * 16 + quad * 4 + reg;
                    atomicAdd(&plds[rl * 2 + 0], p0);
                    atomicAdd(&plds[rl * 2 + 1], p1);
                }
            }
        }
        __syncthreads();
        int r = t >> 1, c = t & 1;
        int gr = rowBase + r;
        if (gr < n)
            part[((size_t)blockIdx.y * n + gr) * 2 + c] = plds[t];
        return;
    }

#pragma unroll
    for (int i = 0; i < 4; ++i) {
#pragma unroll
        for (int reg = 0; reg < 4; ++reg) {
            int gr = rowBase + wr * 64 + i * 16 + quad * 4 + reg;
            if (gr < n) {
                float sc = (EPI == 0 && rowScale) ? rowScale[gr] : 1.f;
#pragma unroll
                for (int j = 0; j < 4; ++j) {
                    int gc = colBase + wc * 64 + j * 16 + ml;
                    float v = acc[i][j][reg];
                    if (EPI == 1) v += bias[gc];
                    C[(size_t)gr * strideC + gc] = convert_out(v * sc, (OutT*)nullptr);
                }
            }
        }
    }
}

// ---------------- aggregation (R8 pair-gather) ----------------
// Wave = 1 node; two 32-lane halves each gather a DIFFERENT edge per VMEM
// instruction (4 B/lane). Edge ids via __shfl; combine with __shfl_xor(32).

// 64-dim bf16 rows: lane32 covers cols [lane32*2, +2).
__launch_bounds__(256)
__global__ void aggregate64(const bf16* __restrict__ xs, const int* __restrict__ rp,
                            const int* __restrict__ col, const float* __restrict__ dinv,
                            bf16* __restrict__ out, int n) {
    int gid  = blockIdx.x * 256 + threadIdx.x;
    int v    = gid >> 6;
    int lane = gid & 63;
    if (v >= n) return;
    int lane32 = lane & 31;
    int half   = lane >> 5;
    float di = dinv[v];
    int b = rp[v], e = rp[v + 1];
    int deg = e - b;
    const bf16* base = xs + lane32 * 2;
    float ax = 0.f, ay = 0.f;
    for (int j0 = 0; j0 < deg; j0 += 64) {
        int rem = deg - j0; if (rem > 64) rem = 64;
        int cj = (lane < rem) ? col[b + j0 + lane] : 0;
        int jj = 0;
        for (; jj + 8 <= rem; jj += 8) {
            int s0 = __shfl(cj, jj + 0 + half, 64);
            int s1 = __shfl(cj, jj + 2 + half, 64);
            int s2 = __shfl(cj, jj + 4 + half, 64);
            int s3 = __shfl(cj, jj + 6 + half, 64);
            bf16x2 m0 = *(const bf16x2*)(base + (size_t)s0 * 64);
            bf16x2 m1 = *(const bf16x2*)(base + (size_t)s1 * 64);
            bf16x2 m2 = *(const bf16x2*)(base + (size_t)s2 * 64);
            bf16x2 m3 = *(const bf16x2*)(base + (size_t)s3 * 64);
            ax += ((float)m0[0] + (float)m1[0]) + ((float)m2[0] + (float)m3[0]);
            ay += ((float)m0[1] + (float)m1[1]) + ((float)m2[1] + (float)m3[1]);
        }
        for (; jj + 2 <= rem; jj += 2) {
            int s = __shfl(cj, jj + half, 64);
            bf16x2 m = *(const bf16x2*)(base + (size_t)s * 64);
            ax += (float)m[0]; ay += (float)m[1];
        }
        if (jj < rem) {
            int s = __shfl(cj, jj, 64);
            bf16x2 m = *(const bf16x2*)(base + (size_t)s * 64);
            if (half == 0) { ax += (float)m[0]; ay += (float)m[1]; }
        }
    }
    ax += __shfl_xor(ax, 32, 64);
    ay += __shfl_xor(ay, 32, 64);
    if (half == 0) {
        bf16x2 mv = *(const bf16x2*)(base + (size_t)v * 64);
        bf16x2 o;
        o[0] = (bf16)(di * (ax + (float)mv[0]));
        o[1] = (bf16)(di * (ay + (float)mv[1]));
        *(bf16x2*)(out + (size_t)v * 64 + lane32 * 2) = o;
    }
}

// 128-dim fp8 rows: lane32 covers cols [lane32*4, +4).
__launch_bounds__(256)
__global__ void aggregate_fp8(const fp8s* __restrict__ xs, const int* __restrict__ rp,
                              const int* __restrict__ col, const float* __restrict__ dinv,
                              const float* __restrict__ bias, bf16* __restrict__ out,
                              int outStride, int n) {
    int gid  = blockIdx.x * 256 + threadIdx.x;
    int v    = gid >> 6;
    int lane = gid & 63;
    if (v >= n) return;
    int lane32 = lane & 31;
    int half   = lane >> 5;
    float di = dinv[v];
    int b = rp[v], e = rp[v + 1];
    int deg = e - b;
    const fp8s* base = xs + lane32 * 4;
    float a0 = 0.f, a1 = 0.f, a2 = 0.f, a3 = 0.f;
    for (int j0 = 0; j0 < deg; j0 += 64) {
        int rem = deg - j0; if (rem > 64) rem = 64;
        int cj = (lane < rem) ? col[b + j0 + lane] : 0;
        int jj = 0;
        for (; jj + 8 <= rem; jj += 8) {
            int s0 = __shfl(cj, jj + 0 + half, 64);
            int s1 = __shfl(cj, jj + 2 + half, 64);
            int s2 = __shfl(cj, jj + 4 + half, 64);
            int s3 = __shfl(cj, jj + 6 + half, 64);
            float4 f0 = fp8x4_to_f4(*(const unsigned*)(base + (size_t)s0 * 128));
            float4 f1 = fp8x4_to_f4(*(const unsigned*)(base + (size_t)s1 * 128));
            float4 f2 = fp8x4_to_f4(*(const unsigned*)(base + (size_t)s2 * 128));
            float4 f3 = fp8x4_to_f4(*(const unsigned*)(base + (size_t)s3 * 128));
            a0 += (f0.x + f1.x) + (f2.x + f3.x);
            a1 += (f0.y + f1.y) + (f2.y + f3.y);
            a2 += (f0.z + f1.z) + (f2.z + f3.z);
            a3 += (f0.w + f1.w) + (f2.w + f3.w);
        }
        for (; jj + 2 <= rem; jj += 2) {
            int s = __shfl(cj, jj + half, 64);
            float4 f = fp8x4_to_f4(*(const unsigned*)(base + (size_t)s * 128));
            a0 += f.x; a1 += f.y; a2 += f.z; a3 += f.w;
        }
        if (jj < rem) {
            int s = __shfl(cj, jj, 64);
            float4 f = fp8x4_to_f4(*(const unsigned*)(base + (size_t)s * 128));
            if (half == 0) { a0 += f.x; a1 += f.y; a2 += f.z; a3 += f.w; }
        }
    }
    a0 += __shfl_xor(a0, 32, 64);
    a1 += __shfl_xor(a1, 32, 64);
    a2 += __shfl_xor(a2, 32, 64);
    a3 += __shfl_xor(a3, 32, 64);
    if (half == 0) {
        float4 fv = fp8x4_to_f4(*(const unsigned*)(base + (size_t)v * 128));
        float4 bb = *(const float4*)(bias + lane32 * 4);
        bf16x4 o;
        o[0] = (bf16)(di * (a0 + fv.x) + bb.x);
        o[1] = (bf16)(di * (a1 + fv.y) + bb.y);
        o[2] = (bf16)(di * (a2 + fv.z) + bb.z);
        o[3] = (bf16)(di * (a3 + fv.w) + bb.w);
        *(bf16x4*)(out + (size_t)v * outStride + lane32 * 4) = o;
    }
}

// ---------------- softmax final ----------------
__launch_bounds__(256)
__global__ void softmax_final(const float* __restrict__ part, const float* __restrict__ lb2,
                              float* __restrict__ out, int n) {
    int i = blockIdx.x * 256 + threadIdx.x;
    if (i >= n) return;
    size_t seg = (size_t)n * 2;
    float2 p0 = *(const float2*)(part + (size_t)i * 2);
    float2 p1 = *(const float2*)(part + seg + (size_t)i * 2);
    float2 p2 = *(const float2*)(part + 2 * seg + (size_t)i * 2);
    float l0 = p0.x + p1.x + p2.x + lb2[0];
    float l1 = p0.y + p1.y + p2.y + lb2[1];
    *(float2*)(out + (size_t)i * 2) = make_float2(l0, l1);
    float m  = fmaxf(l0, l1);
    float e0 = expf(l0 - m), e1 = expf(l1 - m);
    float inv = 1.f / (e0 + e1);
    *(float2*)(out + seg + (size_t)i * 2) = make_float2(e0 * inv, e1 * inv);
}

extern "C" void kernel_launch(void* const* d_in, const int* in_sizes, int n_in,
                              void* d_out, int out_size, void* d_ws, size_t ws_size,
                              hipStream_t stream) {
    const float* x   = (const float*)d_in[0];
    const int*   ei  = (const int*)d_in[1];
    const float* W1  = (const float*)d_in[2];
    const float* b1  = (const float*)d_in[3];
    const float* W2  = (const float*)d_in[4];
    const float* b2  = (const float*)d_in[5];
    const float* W3  = (const float*)d_in[6];
    const float* b3  = (const float*)d_in[7];
    const float* lW1 = (const float*)d_in[8];
    const float* lb1 = (const float*)d_in[9];
    const float* lW2 = (const float*)d_in[10];
    const float* lb2 = (const float*)d_in[11];
    float* out = (float*)d_out;

    int N = in_sizes[0] / 64;
    int E = in_sizes[1] / 2;
    const int* src = ei;
    const int* dst = ei + E;

    char* ws = (char*)d_ws;
    size_t off = 0;
    auto take = [&](size_t bytes) -> char* {
        char* p = ws + off;
        off += (bytes + 255) & ~(size_t)255;
        return p;
    };
    int nBlk  = (N + 255) / 256;
    int nbuck = nBlk;
    int*   cnt    = (int*)take((size_t)N * 4);         // fallback only
    int*   fill   = (int*)take((size_t)N * 4);         // fallback only
    int*   rp     = (int*)take((size_t)(N + 1) * 4);
    float* dinv   = (float*)take((size_t)N * 4);
    int*   bsum   = (int*)take((size_t)nBlk * 4);      // fallback only
    int*   hist2d = (int*)take((size_t)256 * 256 * 4);
    int*   tailA  = (int*)take((size_t)nbuck * 4);
    int*   bbase  = (int*)take((size_t)(nbuck + 1) * 4);
    int*   col    = (int*)take((size_t)E * 4);
    unsigned int* pairs = (unsigned int*)take((size_t)E * 4);
    bf16*  xs0    = (bf16*)take((size_t)N * 64 * 2);
    bf16*  ax     = (bf16*)take((size_t)N * 64 * 2);
    bf16*  Wt1    = (bf16*)take((size_t)64 * 128 * 2);
    bf16*  Wt2    = (bf16*)take((size_t)128 * 128 * 2);
    bf16*  Wt3    = (bf16*)take((size_t)128 * 128 * 2);
    bf16*  lW1_bf = (bf16*)take((size_t)384 * 384 * 2);
    fp8s*  xw8    = (fp8s*)take((size_t)N * 128);
    bf16*  hcat   = (bf16*)take((size_t)N * 384 * 2);
    float* part   = (float*)take((size_t)N * 2 * 3 * 4);

    // CSR build (4 dispatches, no memset, no global-atomic hist)
    if (nbuck <= 256 && N <= 65536) {
        bucket_hist<<<256, 256, 0, stream>>>(dst, hist2d, E);
        scan_tails<<<1, 256, 0, stream>>>(hist2d, tailA, bbase, nbuck, E);
        bin_pairs<<<nbuck, 256, 0, stream>>>(src, dst, tailA, pairs, E, nbuck);
        csr_fill_full<<<nbuck, 256, 0, stream>>>(pairs, bbase, rp, dinv, col, N, E);
    } else {
        init_kernel<<<nBlk, 256, 0, stream>>>(cnt, fill, N);
        hist_kernel<<<(E + 255) / 256, 256, 0, stream>>>(dst, cnt, E);
        block_reduce<<<nBlk, 256, 0, stream>>>(cnt, bsum, N);
        scan_bsums<<<1, 256, 0, stream>>>(bsum, nBlk);
        write_rp<<<nBlk, 256, 0, stream>>>(cnt, bsum, rp, dinv, N, E);
        fill_kernel<<<(E + 255) / 256, 256, 0, stream>>>(src, dst, rp, fill, col, E);
    }

    // prep (weights + dinv-scaled x cast, one launch)
    int prepElems = 188416 + N * 64;
    prep_all<<<(prepElems + 255) / 256, 256, 0, stream>>>(
        W1, W2, W3, lW1, x, dinv, Wt1, Wt2, Wt3, lW1_bf, xs0, N * 64);

    int gemmBlocks = (N + 127) / 128;
    int aggBlocks  = (N + 3) / 4;

    // conv1: aggregate first (64-dim bf16), then GEMM with bias epilogue
    aggregate64<<<aggBlocks, 256, 0, stream>>>(xs0, rp, col, dinv, ax, N);
    mfma_gemm<1, bf16><<<dim3(gemmBlocks, 1), 256, 0, stream>>>(
        ax, 64, 64, Wt1, b1, nullptr, hcat + 0, 384, N);
    // conv2: GEMM -> fp8 xw (rows pre-scaled by dinv), aggregate fp8 (+bias)
    mfma_gemm<0, fp8s><<<dim3(gemmBlocks, 1), 256, 0, stream>>>(
        hcat + 0, 384, 128, Wt2, nullptr, dinv, xw8, 128, N);
    aggregate_fp8<<<aggBlocks, 256, 0, stream>>>(xw8, rp, col, dinv, b2, hcat + 128, 384, N);
    // conv3
    mfma_gemm<0, fp8s><<<dim3(gemmBlocks, 1), 256, 0, stream>>>(
        hcat + 128, 384, 128, Wt3, nullptr, dinv, xw8, 128, N);
    aggregate_fp8<<<aggBlocks, 256, 0, stream>>>(xw8, rp, col, dinv, b3, hcat + 256, 384, N);

    // MLP head: linear1+relu+linear2 fused (partial logits per y), then softmax
    mfma_gemm<3, bf16><<<dim3(gemmBlocks, 3), 256, 0, stream>>>(
        hcat, 384, 384, lW1_bf, lb1, nullptr, (bf16*)nullptr, 0, N, lW2, part);
    softmax_final<<<(N + 255) / 256, 256, 0, stream>>>(part, lb2, out, N);
}

// Round 13
// 271.269 us; speedup vs baseline: 1.3754x; 1.0085x over previous
//
#include <hip/hip_runtime.h>
#include <hip/hip_bf16.h>
#include <hip/hip_fp8.h>
#include <cmath>

// ---------------------------------------------------------------------------
// Round 13 (base: R11 @ 273.6us; R12's fp8-xs0 REVERTED — layer-1 input
// quantization compounds through the whole network, absmax 0.203 > 0.114):
//   - xs0 back to bf16; aggregate64 = R8 pair-gather (R11-proven numerics).
//   - KEPT from R12 (numerics-neutral): weight prep merged into hist launch;
//     xs0 produced coalesced inside csr_fill_full. 13 -> 12 dispatches.
//   - (R11) 128-dim fp8 pair-gather aggregates; R9 fused linear1/2 head;
//     fp8 xw; bf16 MFMA 128x128/BK32 GEMMs, global_load_lds w16.
// ---------------------------------------------------------------------------

typedef __bf16 bf16;
typedef __bf16 bf16x2 __attribute__((ext_vector_type(2)));
typedef __bf16 bf16x4 __attribute__((ext_vector_type(4)));
typedef __bf16 bf16x8 __attribute__((ext_vector_type(8)));
typedef float  f32x4  __attribute__((ext_vector_type(4)));
typedef unsigned char fp8s;   // e4m3 storage byte

__device__ __forceinline__ void load_lds16(const bf16* g, bf16* l) {
    __builtin_amdgcn_global_load_lds(
        (const __attribute__((address_space(1))) void*)g,
        (__attribute__((address_space(3))) void*)l, 16, 0, 0);
}

__device__ __forceinline__ bf16 convert_out(float v, bf16*) { return (bf16)v; }
__device__ __forceinline__ fp8s convert_out(float v, fp8s*) {
    __hip_fp8_e4m3 q(v); return (fp8s)q.__x;
}

__device__ __forceinline__ float4 fp8x4_to_f4(unsigned int p) {
    __hip_fp8x2_e4m3 lo, hi;
    lo.__x = (__hip_fp8x2_storage_t)(p & 0xffffu);
    hi.__x = (__hip_fp8x2_storage_t)(p >> 16);
    float2 a = (float2)lo, c = (float2)hi;
    return make_float4(a.x, a.y, c.x, c.y);
}

// ---------------- CSR build (bucketed, N <= 65536 path) ----------------

// blocks [0,256): per-block partial hists (no init, no global atomics).
// blocks [256, 256+736): weight transpose/cast (independent; merged dispatch).
__launch_bounds__(256)
__global__ void hist_and_prep(const int* __restrict__ dst, int* __restrict__ hist2d, int e,
                              const float* __restrict__ W1, const float* __restrict__ W2,
                              const float* __restrict__ W3, const float* __restrict__ lW1,
                              bf16* __restrict__ Wt1, bf16* __restrict__ Wt2,
                              bf16* __restrict__ Wt3, bf16* __restrict__ lW1_bf) {
    int t = threadIdx.x;
    if (blockIdx.x < 256) {
        __shared__ int h[256];
        h[t] = 0;
        __syncthreads();
        for (int i = blockIdx.x * 256 + t; i < e; i += 256 * 256)
            atomicAdd(&h[dst[i] >> 8], 1);
        __syncthreads();
        hist2d[blockIdx.x * 256 + t] = h[t];
    } else {
        int i = (blockIdx.x - 256) * 256 + t;
        if (i < 8192) {
            int k = i >> 7, c = i & 127; Wt1[c * 64 + k] = (bf16)W1[i];
        } else if (i < 24576) {
            int j = i - 8192; int k = j >> 7, c = j & 127; Wt2[c * 128 + k] = (bf16)W2[j];
        } else if (i < 40960) {
            int j = i - 24576; int k = j >> 7, c = j & 127; Wt3[c * 128 + k] = (bf16)W3[j];
        } else if (i < 188416) {
            int j = i - 40960; lW1_bf[j] = (bf16)lW1[j];
        }
    }
}

// column-sum the 256 partial hists, exclusive scan -> tailA + bbase
__launch_bounds__(256)
__global__ void scan_tails(const int* __restrict__ hist2d, int* __restrict__ tailA,
                           int* __restrict__ bbase, int nbuck, int etot) {
    __shared__ int s[256];
    int t = threadIdx.x;
    int v = 0;
    for (int b = 0; b < 256; ++b) v += hist2d[b * 256 + t];
    s[t] = v;
    __syncthreads();
#pragma unroll
    for (int off = 1; off < 256; off <<= 1) {
        int tmp = (t >= off) ? s[t - off] : 0;
        __syncthreads();
        s[t] += tmp;
        __syncthreads();
    }
    int excl = s[t] - v;
    if (t < nbuck) { tailA[t] = excl; bbase[t] = excl; }
    if (t == 0) bbase[nbuck] = etot;
}

__launch_bounds__(256)
__global__ void bin_pairs(const int* __restrict__ src, const int* __restrict__ dst,
                          int* __restrict__ tail, unsigned int* __restrict__ pairs,
                          int e, int nbuck) {
    __shared__ int hist[256], base[256], cur[256];
    int t = threadIdx.x;
    hist[t] = 0; cur[t] = 0;
    __syncthreads();
    int perBlock = (e + gridDim.x - 1) / gridDim.x;
    int lo = blockIdx.x * perBlock;
    int hi = lo + perBlock; if (hi > e) hi = e;
    for (int i = lo + t; i < hi; i += 256)
        atomicAdd(&hist[dst[i] >> 8], 1);
    __syncthreads();
    if (t < nbuck && hist[t] > 0) base[t] = atomicAdd(&tail[t], hist[t]);
    __syncthreads();
    for (int i = lo + t; i < hi; i += 256) {
        int d = dst[i];
        int b = d >> 8;
        int r = atomicAdd(&cur[b], 1);
        pairs[base[b] + r] = (unsigned)src[i] | ((unsigned)(d & 255) << 16);
    }
}

// one block per bucket: per-node counts from pairs -> rp + dinv; LDS-window
// scatter -> coalesced col; then xs0 = bf16(dinv * x) for its 256 nodes.
#define FILL_CAP 6144
__launch_bounds__(256)
__global__ void csr_fill_full(const unsigned int* __restrict__ pairs,
                              const int* __restrict__ bbase,
                              const float* __restrict__ x,
                              int* __restrict__ rp, float* __restrict__ dinv,
                              int* __restrict__ col, bf16* __restrict__ xs0,
                              int n, int etot) {
    __shared__ int cnt[256];
    __shared__ int ofs[256];
    __shared__ int ss[256];
    __shared__ float dinv_l[256];
    __shared__ int win[FILL_CAP];
    int b = blockIdx.x, t = threadIdx.x;
    int nodeBase = b << 8;
    int nhi = n - nodeBase; if (nhi > 256) nhi = 256;
    int lo = bbase[b];
    int bcountE = bbase[b + 1] - lo;
    cnt[t] = 0;
    __syncthreads();
    for (int i = t; i < bcountE; i += 256)
        atomicAdd(&cnt[pairs[lo + i] >> 16], 1);
    __syncthreads();
    int myc = cnt[t];
    ss[t] = myc;
    __syncthreads();
#pragma unroll
    for (int off = 1; off < 256; off <<= 1) {
        int tmp = (t >= off) ? ss[t - off] : 0;
        __syncthreads();
        ss[t] += tmp;
        __syncthreads();
    }
    int excl = ss[t] - myc;
    ofs[t] = excl;
    int node = nodeBase + t;
    float d = rsqrtf((float)(myc + 1));
    dinv_l[t] = d;
    if (node < n) {
        rp[node]   = lo + excl;
        dinv[node] = d;                          // +1 self-loop
        if (node == n - 1) rp[n] = etot;
    }
    cnt[t] = 0;
    __syncthreads();
    if (bcountE <= FILL_CAP) {
        for (int i = t; i < bcountE; i += 256) {
            unsigned p = pairs[lo + i];
            int dl = (int)(p >> 16);
            int r = atomicAdd(&cnt[dl], 1);
            win[ofs[dl] + r] = (int)(p & 0xffffu);
        }
        __syncthreads();
        for (int i = t; i < bcountE; i += 256) col[lo + i] = win[i];
    } else {
        for (int i = t; i < bcountE; i += 256) {
            unsigned p = pairs[lo + i];
            int dl = (int)(p >> 16);
            int r = atomicAdd(&cnt[dl], 1);
            col[lo + ofs[dl] + r] = (int)(p & 0xffffu);
        }
    }
    // xs0 = bf16(dinv[row] * x[row]) for this block's nodes (coalesced)
    int tot = nhi * 64;
    const float* xb = x + (size_t)nodeBase * 64;
    bf16* ob = xs0 + (size_t)nodeBase * 64;
    for (int idx = t; idx < tot; idx += 256)
        ob[idx] = (bf16)(xb[idx] * dinv_l[idx >> 6]);
}

// -------- fallback CSR build for N > 65536 (not used at this size) --------

__launch_bounds__(256)
__global__ void init_kernel(int* __restrict__ cnt, int* __restrict__ fill, int n) {
    int i = blockIdx.x * 256 + threadIdx.x;
    if (i < n) { cnt[i] = 1; fill[i] = 0; }
}

__launch_bounds__(256)
__global__ void hist_kernel(const int* __restrict__ dst, int* __restrict__ cnt, int e) {
    int i = blockIdx.x * 256 + threadIdx.x;
    if (i < e) atomicAdd(&cnt[dst[i]], 1);
}

__launch_bounds__(256)
__global__ void block_reduce(const int* __restrict__ cnt, int* __restrict__ bsum, int n) {
    __shared__ int s[256];
    int t = threadIdx.x;
    int i = blockIdx.x * 256 + t;
    int v = (i < n) ? cnt[i] - 1 : 0;
    s[t] = v;
    __syncthreads();
#pragma unroll
    for (int off = 128; off > 0; off >>= 1) {
        if (t < off) s[t] += s[t + off];
        __syncthreads();
    }
    if (t == 0) bsum[blockIdx.x] = s[0];
}

__launch_bounds__(256)
__global__ void scan_bsums(int* __restrict__ bsum, int nb) {
    __shared__ int s[256];
    int t = threadIdx.x;
    int v = (t < nb) ? bsum[t] : 0;
    s[t] = v;
    __syncthreads();
#pragma unroll
    for (int off = 1; off < 256; off <<= 1) {
        int tmp = (t >= off) ? s[t - off] : 0;
        __syncthreads();
        s[t] += tmp;
        __syncthreads();
    }
    if (t < nb) bsum[t] = s[t] - v;
}

__launch_bounds__(256)
__global__ void write_rp_fb(const int* __restrict__ cnt, const int* __restrict__ bsum,
                            const float* __restrict__ x,
                            int* __restrict__ rp, float* __restrict__ dinv,
                            bf16* __restrict__ xs0, int n, int etot) {
    __shared__ int s[256];
    int t = threadIdx.x;
    int i = blockIdx.x * 256 + t;
    int c = (i < n) ? cnt[i] : 1;
    int v = c - 1;
    s[t] = v;
    __syncthreads();
#pragma unroll
    for (int off = 1; off < 256; off <<= 1) {
        int tmp = (t >= off) ? s[t - off] : 0;
        __syncthreads();
        s[t] += tmp;
        __syncthreads();
    }
    if (i < n) {
        rp[i]   = bsum[blockIdx.x] + s[t] - v;
        float d = rsqrtf((float)c);
        dinv[i] = d;
        for (int k = 0; k < 64; ++k)
            xs0[(size_t)i * 64 + k] = (bf16)(x[(size_t)i * 64 + k] * d);
        if (i == n - 1) rp[n] = etot;
    }
}

__launch_bounds__(256)
__global__ void fill_kernel(const int* __restrict__ src, const int* __restrict__ dst,
                            const int* __restrict__ rp, int* __restrict__ fill,
                            int* __restrict__ col, int e) {
    int i = blockIdx.x * 256 + threadIdx.x;
    if (i < e) {
        int d = dst[i];
        int pos = rp[d] + atomicAdd(&fill[d], 1);
        col[pos] = src[i];
    }
}

// ---------------- MFMA GEMM ----------------
// EPI: 0 = rowScale only, 1 = +bias, 3 = LOGITS (relu(v+bias) @ lW2^T -> part)
template<int EPI, typename OutT>
__launch_bounds__(256, 4)
__global__ void mfma_gemm(const bf16* __restrict__ A, int strideA, int K,
                          const bf16* __restrict__ Bt,
                          const float* __restrict__ bias,
                          const float* __restrict__ rowScale,
                          OutT* __restrict__ C, int strideC, int n,
                          const float* __restrict__ lW2 = nullptr,
                          float* __restrict__ part = nullptr) {
    __shared__ bf16 As[128 * 32];
    __shared__ bf16 Bs[128 * 32];
    __shared__ float plds[128 * 2];   // only used by EPI==3
    int t = threadIdx.x;
    int rowBase = blockIdx.x * 128;
    int colBase = blockIdx.y * 128;

    int lane = t & 63;
    int wv   = t >> 6;
    int wr   = wv >> 1, wc = wv & 1;
    int ml   = lane & 15, quad = lane >> 4;

    if (EPI == 3) plds[t] = 0.f;

    f32x4 acc[4][4];
#pragma unroll
    for (int i = 0; i < 4; ++i)
#pragma unroll
        for (int j = 0; j < 4; ++j) acc[i][j] = (f32x4){0.f, 0.f, 0.f, 0.f};

    int srow0 = wv * 32 + (lane >> 2);
    int cchunk = lane & 3;

    for (int kt = 0; kt < K; kt += 32) {
        __syncthreads();
#pragma unroll
        for (int inst = 0; inst < 2; ++inst) {
            int r  = srow0 + inst * 16;
            int gc = (cchunk ^ (r & 3)) * 8;
            int gr = rowBase + r; if (gr >= n) gr = n - 1;
            load_lds16(A + (size_t)gr * strideA + kt + gc,
                       &As[(wv * 128 + inst * 64) * 8]);
            int br = colBase + r;
            load_lds16(Bt + (size_t)br * K + kt + gc,
                       &Bs[(wv * 128 + inst * 64) * 8]);
        }
        __syncthreads();
        bf16x8 af[4], bfv[4];
#pragma unroll
        for (int i = 0; i < 4; ++i) {
            int ra = wr * 64 + i * 16 + ml;
            int rb = wc * 64 + i * 16 + ml;
            af[i]  = *(const bf16x8*)&As[(ra * 4 + (quad ^ (ra & 3))) * 8];
            bfv[i] = *(const bf16x8*)&Bs[(rb * 4 + (quad ^ (rb & 3))) * 8];
        }
#pragma unroll
        for (int i = 0; i < 4; ++i)
#pragma unroll
            for (int j = 0; j < 4; ++j)
                acc[i][j] = __builtin_amdgcn_mfma_f32_16x16x32_bf16(
                    af[i], bfv[j], acc[i][j], 0, 0, 0);
    }

    if (EPI == 3) {
        float b4[4], w0[4], w1[4];
#pragma unroll
        for (int j = 0; j < 4; ++j) {
            int gc = colBase + wc * 64 + j * 16 + ml;
            b4[j] = bias[gc];
            w0[j] = lW2[gc];
            w1[j] = lW2[384 + gc];
        }
#pragma unroll
        for (int i = 0; i < 4; ++i) {
#pragma unroll
            for (int reg = 0; reg < 4; ++reg) {
                float p0 = 0.f, p1 = 0.f;
#pragma unroll
                for (int j = 0; j < 4; ++j) {
                    float v = fmaxf(acc[i][j][reg] + b4[j], 0.f);
                    p0 += v * w0[j];
                    p1 += v * w1[j];
                }
#pragma unroll
                for (int m = 1; m < 16; m <<= 1) {
                    p0 += __shfl_xor(p0, m, 64);
                    p1 += __shfl_xor(p1, m, 64);
                }
                if (ml == 0) {
                    int rl = wr * 64 + i * 16 + quad * 4 + reg;
                    atomicAdd(&plds[rl * 2 + 0], p0);
                    atomicAdd(&plds[rl * 2 + 1], p1);
                }
            }
        }
        __syncthreads();
        int r = t >> 1, c = t & 1;
        int gr = rowBase + r;
        if (gr < n)
            part[((size_t)blockIdx.y * n + gr) * 2 + c] = plds[t];
        return;
    }

#pragma unroll
    for (int i = 0; i < 4; ++i) {
#pragma unroll
        for (int reg = 0; reg < 4; ++reg) {
            int gr = rowBase + wr * 64 + i * 16 + quad * 4 + reg;
            if (gr < n) {
                float sc = (EPI == 0 && rowScale) ? rowScale[gr] : 1.f;
#pragma unroll
                for (int j = 0; j < 4; ++j) {
                    int gc = colBase + wc * 64 + j * 16 + ml;
                    float v = acc[i][j][reg];
                    if (EPI == 1) v += bias[gc];
                    C[(size_t)gr * strideC + gc] = convert_out(v * sc, (OutT*)nullptr);
                }
            }
        }
    }
}

// ---------------- aggregation (R8 pair-gather) ----------------
// Wave = 1 node; two 32-lane halves each gather a DIFFERENT edge per VMEM
// instruction (4 B/lane). Edge ids via __shfl; combine with __shfl_xor(32).

// 64-dim bf16 rows: lane32 covers cols [lane32*2, +2).
__launch_bounds__(256)
__global__ void aggregate64(const bf16* __restrict__ xs, const int* __restrict__ rp,
                            const int* __restrict__ col, const float* __restrict__ dinv,
                            bf16* __restrict__ out, int n) {
    int gid  = blockIdx.x * 256 + threadIdx.x;
    int v    = gid >> 6;
    int lane = gid & 63;
    if (v >= n) return;
    int lane32 = lane & 31;
    int half   = lane >> 5;
    float di = dinv[v];
    int b = rp[v], e = rp[v + 1];
    int deg = e - b;
    const bf16* base = xs + lane32 * 2;
    float ax = 0.f, ay = 0.f;
    for (int j0 = 0; j0 < deg; j0 += 64) {
        int rem = deg - j0; if (rem > 64) rem = 64;
        int cj = (lane < rem) ? col[b + j0 + lane] : 0;
        int jj = 0;
        for (; jj + 8 <= rem; jj += 8) {
            int s0 = __shfl(cj, jj + 0 + half, 64);
            int s1 = __shfl(cj, jj + 2 + half, 64);
            int s2 = __shfl(cj, jj + 4 + half, 64);
            int s3 = __shfl(cj, jj + 6 + half, 64);
            bf16x2 m0 = *(const bf16x2*)(base + (size_t)s0 * 64);
            bf16x2 m1 = *(const bf16x2*)(base + (size_t)s1 * 64);
            bf16x2 m2 = *(const bf16x2*)(base + (size_t)s2 * 64);
            bf16x2 m3 = *(const bf16x2*)(base + (size_t)s3 * 64);
            ax += ((float)m0[0] + (float)m1[0]) + ((float)m2[0] + (float)m3[0]);
            ay += ((float)m0[1] + (float)m1[1]) + ((float)m2[1] + (float)m3[1]);
        }
        for (; jj + 2 <= rem; jj += 2) {
            int s = __shfl(cj, jj + half, 64);
            bf16x2 m = *(const bf16x2*)(base + (size_t)s * 64);
            ax += (float)m[0]; ay += (float)m[1];
        }
        if (jj < rem) {
            int s = __shfl(cj, jj, 64);
            bf16x2 m = *(const bf16x2*)(base + (size_t)s * 64);
            if (half == 0) { ax += (float)m[0]; ay += (float)m[1]; }
        }
    }
    ax += __shfl_xor(ax, 32, 64);
    ay += __shfl_xor(ay, 32, 64);
    if (half == 0) {
        bf16x2 mv = *(const bf16x2*)(base + (size_t)v * 64);
        bf16x2 o;
        o[0] = (bf16)(di * (ax + (float)mv[0]));
        o[1] = (bf16)(di * (ay + (float)mv[1]));
        *(bf16x2*)(out + (size_t)v * 64 + lane32 * 2) = o;
    }
}

// 128-dim fp8 rows: lane32 covers cols [lane32*4, +4).
__launch_bounds__(256)
__global__ void aggregate_fp8(const fp8s* __restrict__ xs, const int* __restrict__ rp,
                              const int* __restrict__ col, const float* __restrict__ dinv,
                              const float* __restrict__ bias, bf16* __restrict__ out,
                              int outStride, int n) {
    int gid  = blockIdx.x * 256 + threadIdx.x;
    int v    = gid >> 6;
    int lane = gid & 63;
    if (v >= n) return;
    int lane32 = lane & 31;
    int half   = lane >> 5;
    float di = dinv[v];
    int b = rp[v], e = rp[v + 1];
    int deg = e - b;
    const fp8s* base = xs + lane32 * 4;
    float a0 = 0.f, a1 = 0.f, a2 = 0.f, a3 = 0.f;
    for (int j0 = 0; j0 < deg; j0 += 64) {
        int rem = deg - j0; if (rem > 64) rem = 64;
        int cj = (lane < rem) ? col[b + j0 + lane] : 0;
        int jj = 0;
        for (; jj + 8 <= rem; jj += 8) {
            int s0 = __shfl(cj, jj + 0 + half, 64);
            int s1 = __shfl(cj, jj + 2 + half, 64);
            int s2 = __shfl(cj, jj + 4 + half, 64);
            int s3 = __shfl(cj, jj + 6 + half, 64);
            float4 f0 = fp8x4_to_f4(*(const unsigned*)(base + (size_t)s0 * 128));
            float4 f1 = fp8x4_to_f4(*(const unsigned*)(base + (size_t)s1 * 128));
            float4 f2 = fp8x4_to_f4(*(const unsigned*)(base + (size_t)s2 * 128));
            float4 f3 = fp8x4_to_f4(*(const unsigned*)(base + (size_t)s3 * 128));
            a0 += (f0.x + f1.x) + (f2.x + f3.x);
            a1 += (f0.y + f1.y) + (f2.y + f3.y);
            a2 += (f0.z + f1.z) + (f2.z + f3.z);
            a3 += (f0.w + f1.w) + (f2.w + f3.w);
        }
        for (; jj + 2 <= rem; jj += 2) {
            int s = __shfl(cj, jj + half, 64);
            float4 f = fp8x4_to_f4(*(const unsigned*)(base + (size_t)s * 128));
            a0 += f.x; a1 += f.y; a2 += f.z; a3 += f.w;
        }
        if (jj < rem) {
            int s = __shfl(cj, jj, 64);
            float4 f = fp8x4_to_f4(*(const unsigned*)(base + (size_t)s * 128));
            if (half == 0) { a0 += f.x; a1 += f.y; a2 += f.z; a3 += f.w; }
        }
    }
    a0 += __shfl_xor(a0, 32, 64);
    a1 += __shfl_xor(a1, 32, 64);
    a2 += __shfl_xor(a2, 32, 64);
    a3 += __shfl_xor(a3, 32, 64);
    if (half == 0) {
        float4 fv = fp8x4_to_f4(*(const unsigned*)(base + (size_t)v * 128));
        float4 bb = *(const float4*)(bias + lane32 * 4);
        bf16x4 o;
        o[0] = (bf16)(di * (a0 + fv.x) + bb.x);
        o[1] = (bf16)(di * (a1 + fv.y) + bb.y);
        o[2] = (bf16)(di * (a2 + fv.z) + bb.z);
        o[3] = (bf16)(di * (a3 + fv.w) + bb.w);
        *(bf16x4*)(out + (size_t)v * outStride + lane32 * 4) = o;
    }
}

// ---------------- softmax final ----------------
__launch_bounds__(256)
__global__ void softmax_final(const float* __restrict__ part, const float* __restrict__ lb2,
                              float* __restrict__ out, int n) {
    int i = blockIdx.x * 256 + threadIdx.x;
    if (i >= n) return;
    size_t seg = (size_t)n * 2;
    float2 p0 = *(const float2*)(part + (size_t)i * 2);
    float2 p1 = *(const float2*)(part + seg + (size_t)i * 2);
    float2 p2 = *(const float2*)(part + 2 * seg + (size_t)i * 2);
    float l0 = p0.x + p1.x + p2.x + lb2[0];
    float l1 = p0.y + p1.y + p2.y + lb2[1];
    *(float2*)(out + (size_t)i * 2) = make_float2(l0, l1);
    float m  = fmaxf(l0, l1);
    float e0 = expf(l0 - m), e1 = expf(l1 - m);
    float inv = 1.f / (e0 + e1);
    *(float2*)(out + seg + (size_t)i * 2) = make_float2(e0 * inv, e1 * inv);
}

extern "C" void kernel_launch(void* const* d_in, const int* in_sizes, int n_in,
                              void* d_out, int out_size, void* d_ws, size_t ws_size,
                              hipStream_t stream) {
    const float* x   = (const float*)d_in[0];
    const int*   ei  = (const int*)d_in[1];
    const float* W1  = (const float*)d_in[2];
    const float* b1  = (const float*)d_in[3];
    const float* W2  = (const float*)d_in[4];
    const float* b2  = (const float*)d_in[5];
    const float* W3  = (const float*)d_in[6];
    const float* b3  = (const float*)d_in[7];
    const float* lW1 = (const float*)d_in[8];
    const float* lb1 = (const float*)d_in[9];
    const float* lW2 = (const float*)d_in[10];
    const float* lb2 = (const float*)d_in[11];
    float* out = (float*)d_out;

    int N = in_sizes[0] / 64;
    int E = in_sizes[1] / 2;
    const int* src = ei;
    const int* dst = ei + E;

    char* ws = (char*)d_ws;
    size_t off = 0;
    auto take = [&](size_t bytes) -> char* {
        char* p = ws + off;
        off += (bytes + 255) & ~(size_t)255;
        return p;
    };
    int nBlk  = (N + 255) / 256;
    int nbuck = nBlk;
    int*   cnt    = (int*)take((size_t)N * 4);         // fallback only
    int*   fill   = (int*)take((size_t)N * 4);         // fallback only
    int*   rp     = (int*)take((size_t)(N + 1) * 4);
    float* dinv   = (float*)take((size_t)N * 4);
    int*   bsum   = (int*)take((size_t)nBlk * 4);      // fallback only
    int*   hist2d = (int*)take((size_t)256 * 256 * 4);
    int*   tailA  = (int*)take((size_t)nbuck * 4);
    int*   bbase  = (int*)take((size_t)(nbuck + 1) * 4);
    int*   col    = (int*)take((size_t)E * 4);
    unsigned int* pairs = (unsigned int*)take((size_t)E * 4);
    bf16*  xs0    = (bf16*)take((size_t)N * 64 * 2);
    bf16*  ax     = (bf16*)take((size_t)N * 64 * 2);
    bf16*  Wt1    = (bf16*)take((size_t)64 * 128 * 2);
    bf16*  Wt2    = (bf16*)take((size_t)128 * 128 * 2);
    bf16*  Wt3    = (bf16*)take((size_t)128 * 128 * 2);
    bf16*  lW1_bf = (bf16*)take((size_t)384 * 384 * 2);
    fp8s*  xw8    = (fp8s*)take((size_t)N * 128);
    bf16*  hcat   = (bf16*)take((size_t)N * 384 * 2);
    float* part   = (float*)take((size_t)N * 2 * 3 * 4);

    // CSR build + prep (4 dispatches; weights merged into hist launch,
    // xs0 produced inside csr_fill_full)
    if (nbuck <= 256 && N <= 65536) {
        hist_and_prep<<<256 + 736, 256, 0, stream>>>(
            dst, hist2d, E, W1, W2, W3, lW1, Wt1, Wt2, Wt3, lW1_bf);
        scan_tails<<<1, 256, 0, stream>>>(hist2d, tailA, bbase, nbuck, E);
        bin_pairs<<<nbuck, 256, 0, stream>>>(src, dst, tailA, pairs, E, nbuck);
        csr_fill_full<<<nbuck, 256, 0, stream>>>(pairs, bbase, x, rp, dinv, col, xs0, N, E);
    } else {
        hist_and_prep<<<256 + 736, 256, 0, stream>>>(
            dst, hist2d, E, W1, W2, W3, lW1, Wt1, Wt2, Wt3, lW1_bf);  // weights part
        init_kernel<<<nBlk, 256, 0, stream>>>(cnt, fill, N);
        hist_kernel<<<(E + 255) / 256, 256, 0, stream>>>(dst, cnt, E);
        block_reduce<<<nBlk, 256, 0, stream>>>(cnt, bsum, N);
        scan_bsums<<<1, 256, 0, stream>>>(bsum, nBlk);
        write_rp_fb<<<nBlk, 256, 0, stream>>>(cnt, bsum, x, rp, dinv, xs0, N, E);
        fill_kernel<<<(E + 255) / 256, 256, 0, stream>>>(src, dst, rp, fill, col, E);
    }

    int gemmBlocks = (N + 127) / 128;
    int aggBlocks  = (N + 3) / 4;

    // conv1: aggregate first (64-dim bf16 pair-gather), then GEMM (+b1)
    aggregate64<<<aggBlocks, 256, 0, stream>>>(xs0, rp, col, dinv, ax, N);
    mfma_gemm<1, bf16><<<dim3(gemmBlocks, 1), 256, 0, stream>>>(
        ax, 64, 64, Wt1, b1, nullptr, hcat + 0, 384, N);
    // conv2: GEMM -> fp8 xw (rows pre-scaled by dinv), aggregate fp8 (+bias)
    mfma_gemm<0, fp8s><<<dim3(gemmBlocks, 1), 256, 0, stream>>>(
        hcat + 0, 384, 128, Wt2, nullptr, dinv, xw8, 128, N);
    aggregate_fp8<<<aggBlocks, 256, 0, stream>>>(xw8, rp, col, dinv, b2, hcat + 128, 384, N);
    // conv3
    mfma_gemm<0, fp8s><<<dim3(gemmBlocks, 1), 256, 0, stream>>>(
        hcat + 128, 384, 128, Wt3, nullptr, dinv, xw8, 128, N);
    aggregate_fp8<<<aggBlocks, 256, 0, stream>>>(xw8, rp, col, dinv, b3, hcat + 256, 384, N);

    // MLP head: linear1+relu+linear2 fused (partial logits per y), then softmax
    mfma_gemm<3, bf16><<<dim3(gemmBlocks, 3), 256, 0, stream>>>(
        hcat, 384, 384, lW1_bf, lb1, nullptr, (bf16*)nullptr, 0, N, lW2, part);
    softmax_final<<<(N + 255) / 256, 256, 0, stream>>>(part, lb2, out, N);
}

// Round 15
// 257.204 us; speedup vs baseline: 1.4506x; 1.0547x over previous
//
#include <hip/hip_runtime.h>
#include <hip/hip_bf16.h>
#include <hip/hip_fp8.h>
#include <cmath>

// ---------------------------------------------------------------------------
// Round 15 = R14 resubmitted (R14 bench was an infra failure, no signal).
// Base: R13 @ 271.3us.
//   - CSR build restructured to fixed-capacity buckets (CAP=8192/bucket):
//     bases are b*CAP, so the hist pass + 1-block scan are DELETED. bin_prep
//     reserves runs via one global atomicAdd per bucket per block (gcount
//     zeroed by a 784-B memset); csr_fill_full emits per-node rpS/rpE.
//     Weight casts merged into bin_prep's grid. 12 -> 11 dispatches.
//   - (R13) xs0 bf16 produced inside csr_fill_full; (R11) pair-gather
//     aggregates, fused linear1/2 head, fp8 xw; bf16 MFMA 128x128/BK32
//     GEMMs with global_load_lds w16 + XOR-swizzled LDS.
// ---------------------------------------------------------------------------

typedef __bf16 bf16;
typedef __bf16 bf16x2 __attribute__((ext_vector_type(2)));
typedef __bf16 bf16x4 __attribute__((ext_vector_type(4)));
typedef __bf16 bf16x8 __attribute__((ext_vector_type(8)));
typedef float  f32x4  __attribute__((ext_vector_type(4)));
typedef unsigned char fp8s;   // e4m3 storage byte

#define BUCKET_CAP 8192       // expected load 4096 (Poisson), overflow ~impossible

__device__ __forceinline__ void load_lds16(const bf16* g, bf16* l) {
    __builtin_amdgcn_global_load_lds(
        (const __attribute__((address_space(1))) void*)g,
        (__attribute__((address_space(3))) void*)l, 16, 0, 0);
}

__device__ __forceinline__ bf16 convert_out(float v, bf16*) { return (bf16)v; }
__device__ __forceinline__ fp8s convert_out(float v, fp8s*) {
    __hip_fp8_e4m3 q(v); return (fp8s)q.__x;
}

__device__ __forceinline__ float4 fp8x4_to_f4(unsigned int p) {
    __hip_fp8x2_e4m3 lo, hi;
    lo.__x = (__hip_fp8x2_storage_t)(p & 0xffffu);
    hi.__x = (__hip_fp8x2_storage_t)(p >> 16);
    float2 a = (float2)lo, c = (float2)hi;
    return make_float4(a.x, a.y, c.x, c.y);
}

// ---------------- CSR build (fixed-capacity buckets, N <= 65536) ----------------

// blocks [0,nbuck): bin edges by dst>>8 into pairs[b*CAP ..] — per-block LDS
// hist, one global atomicAdd per touched bucket for the run base.
// blocks [nbuck, nbuck+736): weight transpose/cast (independent work).
__launch_bounds__(256)
__global__ void bin_prep(const int* __restrict__ src, const int* __restrict__ dst,
                         int* __restrict__ gcount, unsigned int* __restrict__ pairs,
                         int e, int nbuck,
                         const float* __restrict__ W1, const float* __restrict__ W2,
                         const float* __restrict__ W3, const float* __restrict__ lW1,
                         bf16* __restrict__ Wt1, bf16* __restrict__ Wt2,
                         bf16* __restrict__ Wt3, bf16* __restrict__ lW1_bf) {
    int t = threadIdx.x;
    if ((int)blockIdx.x >= nbuck) {
        int i = (blockIdx.x - nbuck) * 256 + t;
        if (i < 8192) {
            int k = i >> 7, c = i & 127; Wt1[c * 64 + k] = (bf16)W1[i];
        } else if (i < 24576) {
            int j = i - 8192; int k = j >> 7, c = j & 127; Wt2[c * 128 + k] = (bf16)W2[j];
        } else if (i < 40960) {
            int j = i - 24576; int k = j >> 7, c = j & 127; Wt3[c * 128 + k] = (bf16)W3[j];
        } else if (i < 188416) {
            int j = i - 40960; lW1_bf[j] = (bf16)lW1[j];
        }
        return;
    }
    __shared__ int hist[256], base[256], cur[256];
    hist[t] = 0; cur[t] = 0;
    __syncthreads();
    int perBlock = (e + nbuck - 1) / nbuck;
    int lo = blockIdx.x * perBlock;
    int hi = lo + perBlock; if (hi > e) hi = e;
    for (int i = lo + t; i < hi; i += 256)
        atomicAdd(&hist[dst[i] >> 8], 1);
    __syncthreads();
    if (hist[t] > 0) base[t] = atomicAdd(&gcount[t], hist[t]);
    __syncthreads();
    for (int i = lo + t; i < hi; i += 256) {
        int d = dst[i];
        int b = d >> 8;
        int r = base[b] + atomicAdd(&cur[b], 1);
        if (r < BUCKET_CAP)   // overflow guard (statistically impossible)
            pairs[(size_t)b * BUCKET_CAP + r] = (unsigned)src[i] | ((unsigned)(d & 255) << 16);
    }
}

// one block per bucket (region [b*CAP, b*CAP+gcount[b])): per-node counts ->
// rpS/rpE + dinv; LDS-window scatter -> coalesced col; xs0 = bf16(dinv * x).
#define FILL_CAP 6144
__launch_bounds__(256)
__global__ void csr_fill_full(const unsigned int* __restrict__ pairs,
                              const int* __restrict__ gcount,
                              const float* __restrict__ x,
                              int* __restrict__ rpS, int* __restrict__ rpE,
                              float* __restrict__ dinv,
                              int* __restrict__ col, bf16* __restrict__ xs0, int n) {
    __shared__ int cnt[256];
    __shared__ int ofs[256];
    __shared__ int ss[256];
    __shared__ float dinv_l[256];
    __shared__ int win[FILL_CAP];
    int b = blockIdx.x, t = threadIdx.x;
    int nodeBase = b << 8;
    int nhi = n - nodeBase; if (nhi > 256) nhi = 256;
    int lo = b * BUCKET_CAP;
    int bcountE = gcount[b]; if (bcountE > BUCKET_CAP) bcountE = BUCKET_CAP;
    cnt[t] = 0;
    __syncthreads();
    for (int i = t; i < bcountE; i += 256)
        atomicAdd(&cnt[pairs[lo + i] >> 16], 1);
    __syncthreads();
    int myc = cnt[t];
    ss[t] = myc;
    __syncthreads();
#pragma unroll
    for (int off = 1; off < 256; off <<= 1) {
        int tmp = (t >= off) ? ss[t - off] : 0;
        __syncthreads();
        ss[t] += tmp;
        __syncthreads();
    }
    int excl = ss[t] - myc;
    ofs[t] = excl;
    int node = nodeBase + t;
    float d = rsqrtf((float)(myc + 1));
    dinv_l[t] = d;
    if (node < n) {
        rpS[node] = lo + excl;
        rpE[node] = lo + excl + myc;
        dinv[node] = d;                          // +1 self-loop
    }
    cnt[t] = 0;
    __syncthreads();
    if (bcountE <= FILL_CAP) {
        for (int i = t; i < bcountE; i += 256) {
            unsigned p = pairs[lo + i];
            int dl = (int)(p >> 16);
            int r = atomicAdd(&cnt[dl], 1);
            win[ofs[dl] + r] = (int)(p & 0xffffu);
        }
        __syncthreads();
        for (int i = t; i < bcountE; i += 256) col[lo + i] = win[i];
    } else {
        for (int i = t; i < bcountE; i += 256) {
            unsigned p = pairs[lo + i];
            int dl = (int)(p >> 16);
            int r = atomicAdd(&cnt[dl], 1);
            col[lo + ofs[dl] + r] = (int)(p & 0xffffu);
        }
    }
    // xs0 = bf16(dinv[row] * x[row]) for this block's nodes (coalesced)
    int tot = nhi * 64;
    const float* xb = x + (size_t)nodeBase * 64;
    bf16* ob = xs0 + (size_t)nodeBase * 64;
    for (int idx = t; idx < tot; idx += 256)
        ob[idx] = (bf16)(xb[idx] * dinv_l[idx >> 6]);
}

// -------- fallback CSR build for N > 65536 (not used at this size) --------

__launch_bounds__(256)
__global__ void init_kernel(int* __restrict__ cnt, int* __restrict__ fill, int n) {
    int i = blockIdx.x * 256 + threadIdx.x;
    if (i < n) { cnt[i] = 1; fill[i] = 0; }
}

__launch_bounds__(256)
__global__ void hist_kernel(const int* __restrict__ dst, int* __restrict__ cnt, int e) {
    int i = blockIdx.x * 256 + threadIdx.x;
    if (i < e) atomicAdd(&cnt[dst[i]], 1);
}

__launch_bounds__(256)
__global__ void block_reduce(const int* __restrict__ cnt, int* __restrict__ bsum, int n) {
    __shared__ int s[256];
    int t = threadIdx.x;
    int i = blockIdx.x * 256 + t;
    int v = (i < n) ? cnt[i] - 1 : 0;
    s[t] = v;
    __syncthreads();
#pragma unroll
    for (int off = 128; off > 0; off >>= 1) {
        if (t < off) s[t] += s[t + off];
        __syncthreads();
    }
    if (t == 0) bsum[blockIdx.x] = s[0];
}

__launch_bounds__(256)
__global__ void scan_bsums(int* __restrict__ bsum, int nb) {
    __shared__ int s[256];
    int t = threadIdx.x;
    int v = (t < nb) ? bsum[t] : 0;
    s[t] = v;
    __syncthreads();
#pragma unroll
    for (int off = 1; off < 256; off <<= 1) {
        int tmp = (t >= off) ? s[t - off] : 0;
        __syncthreads();
        s[t] += tmp;
        __syncthreads();
    }
    if (t < nb) bsum[t] = s[t] - v;
}

__launch_bounds__(256)
__global__ void write_rp_fb(const int* __restrict__ cnt, const int* __restrict__ bsum,
                            const float* __restrict__ x,
                            int* __restrict__ rpS, int* __restrict__ rpE,
                            float* __restrict__ dinv,
                            bf16* __restrict__ xs0, int n) {
    __shared__ int s[256];
    int t = threadIdx.x;
    int i = blockIdx.x * 256 + t;
    int c = (i < n) ? cnt[i] : 1;
    int v = c - 1;
    s[t] = v;
    __syncthreads();
#pragma unroll
    for (int off = 1; off < 256; off <<= 1) {
        int tmp = (t >= off) ? s[t - off] : 0;
        __syncthreads();
        s[t] += tmp;
        __syncthreads();
    }
    if (i < n) {
        int start = bsum[blockIdx.x] + s[t] - v;
        rpS[i] = start;
        rpE[i] = start + v;
        float d = rsqrtf((float)c);
        dinv[i] = d;
        for (int k = 0; k < 64; ++k)
            xs0[(size_t)i * 64 + k] = (bf16)(x[(size_t)i * 64 + k] * d);
    }
}

__launch_bounds__(256)
__global__ void fill_kernel(const int* __restrict__ src, const int* __restrict__ dst,
                            const int* __restrict__ rpS, int* __restrict__ fill,
                            int* __restrict__ col, int e) {
    int i = blockIdx.x * 256 + threadIdx.x;
    if (i < e) {
        int d = dst[i];
        int pos = rpS[d] + atomicAdd(&fill[d], 1);
        col[pos] = src[i];
    }
}

// ---------------- MFMA GEMM ----------------
// EPI: 0 = rowScale only, 1 = +bias, 3 = LOGITS (relu(v+bias) @ lW2^T -> part)
template<int EPI, typename OutT>
__launch_bounds__(256, 4)
__global__ void mfma_gemm(const bf16* __restrict__ A, int strideA, int K,
                          const bf16* __restrict__ Bt,
                          const float* __restrict__ bias,
                          const float* __restrict__ rowScale,
                          OutT* __restrict__ C, int strideC, int n,
                          const float* __restrict__ lW2 = nullptr,
                          float* __restrict__ part = nullptr) {
    __shared__ bf16 As[128 * 32];
    __shared__ bf16 Bs[128 * 32];
    __shared__ float plds[128 * 2];   // only used by EPI==3
    int t = threadIdx.x;
    int rowBase = blockIdx.x * 128;
    int colBase = blockIdx.y * 128;

    int lane = t & 63;
    int wv   = t >> 6;
    int wr   = wv >> 1, wc = wv & 1;
    int ml   = lane & 15, quad = lane >> 4;

    if (EPI == 3) plds[t] = 0.f;

    f32x4 acc[4][4];
#pragma unroll
    for (int i = 0; i < 4; ++i)
#pragma unroll
        for (int j = 0; j < 4; ++j) acc[i][j] = (f32x4){0.f, 0.f, 0.f, 0.f};

    int srow0 = wv * 32 + (lane >> 2);
    int cchunk = lane & 3;

    for (int kt = 0; kt < K; kt += 32) {
        __syncthreads();
#pragma unroll
        for (int inst = 0; inst < 2; ++inst) {
            int r  = srow0 + inst * 16;
            int gc = (cchunk ^ (r & 3)) * 8;
            int gr = rowBase + r; if (gr >= n) gr = n - 1;
            load_lds16(A + (size_t)gr * strideA + kt + gc,
                       &As[(wv * 128 + inst * 64) * 8]);
            int br = colBase + r;
            load_lds16(Bt + (size_t)br * K + kt + gc,
                       &Bs[(wv * 128 + inst * 64) * 8]);
        }
        __syncthreads();
        bf16x8 af[4], bfv[4];
#pragma unroll
        for (int i = 0; i < 4; ++i) {
            int ra = wr * 64 + i * 16 + ml;
            int rb = wc * 64 + i * 16 + ml;
            af[i]  = *(const bf16x8*)&As[(ra * 4 + (quad ^ (ra & 3))) * 8];
            bfv[i] = *(const bf16x8*)&Bs[(rb * 4 + (quad ^ (rb & 3))) * 8];
        }
#pragma unroll
        for (int i = 0; i < 4; ++i)
#pragma unroll
            for (int j = 0; j < 4; ++j)
                acc[i][j] = __builtin_amdgcn_mfma_f32_16x16x32_bf16(
                    af[i], bfv[j], acc[i][j], 0, 0, 0);
    }

    if (EPI == 3) {
        float b4[4], w0[4], w1[4];
#pragma unroll
        for (int j = 0; j < 4; ++j) {
            int gc = colBase + wc * 64 + j * 16 + ml;
            b4[j] = bias[gc];
            w0[j] = lW2[gc];
            w1[j] = lW2[384 + gc];
        }
#pragma unroll
        for (int i = 0; i < 4; ++i) {
#pragma unroll
            for (int reg = 0; reg < 4; ++reg) {
                float p0 = 0.f, p1 = 0.f;
#pragma unroll
                for (int j = 0; j < 4; ++j) {
                    float v = fmaxf(acc[i][j][reg] + b4[j], 0.f);
                    p0 += v * w0[j];
                    p1 += v * w1[j];
                }
#pragma unroll
                for (int m = 1; m < 16; m <<= 1) {
                    p0 += __shfl_xor(p0, m, 64);
                    p1 += __shfl_xor(p1, m, 64);
                }
                if (ml == 0) {
                    int rl = wr * 64 + i * 16 + quad * 4 + reg;
                    atomicAdd(&plds[rl * 2 + 0], p0);
                    atomicAdd(&plds[rl * 2 + 1], p1);
                }
            }
        }
        __syncthreads();
        int r = t >> 1, c = t & 1;
        int gr = rowBase + r;
        if (gr < n)
            part[((size_t)blockIdx.y * n + gr) * 2 + c] = plds[t];
        return;
    }

#pragma unroll
    for (int i = 0; i < 4; ++i) {
#pragma unroll
        for (int reg = 0; reg < 4; ++reg) {
            int gr = rowBase + wr * 64 + i * 16 + quad * 4 + reg;
            if (gr < n) {
                float sc = (EPI == 0 && rowScale) ? rowScale[gr] : 1.f;
#pragma unroll
                for (int j = 0; j < 4; ++j) {
                    int gc = colBase + wc * 64 + j * 16 + ml;
                    float v = acc[i][j][reg];
                    if (EPI == 1) v += bias[gc];
                    C[(size_t)gr * strideC + gc] = convert_out(v * sc, (OutT*)nullptr);
                }
            }
        }
    }
}

// ---------------- aggregation (R8 pair-gather) ----------------
// Wave = 1 node; two 32-lane halves each gather a DIFFERENT edge per VMEM
// instruction (4 B/lane). Edge ids via __shfl; combine with __shfl_xor(32).

// 64-dim bf16 rows: lane32 covers cols [lane32*2, +2).
__launch_bounds__(256)
__global__ void aggregate64(const bf16* __restrict__ xs, const int* __restrict__ rpS,
                            const int* __restrict__ rpE,
                            const int* __restrict__ col, const float* __restrict__ dinv,
                            bf16* __restrict__ out, int n) {
    int gid  = blockIdx.x * 256 + threadIdx.x;
    int v    = gid >> 6;
    int lane = gid & 63;
    if (v >= n) return;
    int lane32 = lane & 31;
    int half   = lane >> 5;
    float di = dinv[v];
    int b = rpS[v], e = rpE[v];
    int deg = e - b;
    const bf16* base = xs + lane32 * 2;
    float ax = 0.f, ay = 0.f;
    for (int j0 = 0; j0 < deg; j0 += 64) {
        int rem = deg - j0; if (rem > 64) rem = 64;
        int cj = (lane < rem) ? col[b + j0 + lane] : 0;
        int jj = 0;
        for (; jj + 8 <= rem; jj += 8) {
            int s0 = __shfl(cj, jj + 0 + half, 64);
            int s1 = __shfl(cj, jj + 2 + half, 64);
            int s2 = __shfl(cj, jj + 4 + half, 64);
            int s3 = __shfl(cj, jj + 6 + half, 64);
            bf16x2 m0 = *(const bf16x2*)(base + (size_t)s0 * 64);
            bf16x2 m1 = *(const bf16x2*)(base + (size_t)s1 * 64);
            bf16x2 m2 = *(const bf16x2*)(base + (size_t)s2 * 64);
            bf16x2 m3 = *(const bf16x2*)(base + (size_t)s3 * 64);
            ax += ((float)m0[0] + (float)m1[0]) + ((float)m2[0] + (float)m3[0]);
            ay += ((float)m0[1] + (float)m1[1]) + ((float)m2[1] + (float)m3[1]);
        }
        for (; jj + 2 <= rem; jj += 2) {
            int s = __shfl(cj, jj + half, 64);
            bf16x2 m = *(const bf16x2*)(base + (size_t)s * 64);
            ax += (float)m[0]; ay += (float)m[1];
        }
        if (jj < rem) {
            int s = __shfl(cj, jj, 64);
            bf16x2 m = *(const bf16x2*)(base + (size_t)s * 64);
            if (half == 0) { ax += (float)m[0]; ay += (float)m[1]; }
        }
    }
    ax += __shfl_xor(ax, 32, 64);
    ay += __shfl_xor(ay, 32, 64);
    if (half == 0) {
        bf16x2 mv = *(const bf16x2*)(base + (size_t)v * 64);
        bf16x2 o;
        o[0] = (bf16)(di * (ax + (float)mv[0]));
        o[1] = (bf16)(di * (ay + (float)mv[1]));
        *(bf16x2*)(out + (size_t)v * 64 + lane32 * 2) = o;
    }
}

// 128-dim fp8 rows: lane32 covers cols [lane32*4, +4).
__launch_bounds__(256)
__global__ void aggregate_fp8(const fp8s* __restrict__ xs, const int* __restrict__ rpS,
                              const int* __restrict__ rpE,
                              const int* __restrict__ col, const float* __restrict__ dinv,
                              const float* __restrict__ bias, bf16* __restrict__ out,
                              int outStride, int n) {
    int gid  = blockIdx.x * 256 + threadIdx.x;
    int v    = gid >> 6;
    int lane = gid & 63;
    if (v >= n) return;
    int lane32 = lane & 31;
    int half   = lane >> 5;
    float di = dinv[v];
    int b = rpS[v], e = rpE[v];
    int deg = e - b;
    const fp8s* base = xs + lane32 * 4;
    float a0 = 0.f, a1 = 0.f, a2 = 0.f, a3 = 0.f;
    for (int j0 = 0; j0 < deg; j0 += 64) {
        int rem = deg - j0; if (rem > 64) rem = 64;
        int cj = (lane < rem) ? col[b + j0 + lane] : 0;
        int jj = 0;
        for (; jj + 8 <= rem; jj += 8) {
            int s0 = __shfl(cj, jj + 0 + half, 64);
            int s1 = __shfl(cj, jj + 2 + half, 64);
            int s2 = __shfl(cj, jj + 4 + half, 64);
            int s3 = __shfl(cj, jj + 6 + half, 64);
            float4 f0 = fp8x4_to_f4(*(const unsigned*)(base + (size_t)s0 * 128));
            float4 f1 = fp8x4_to_f4(*(const unsigned*)(base + (size_t)s1 * 128));
            float4 f2 = fp8x4_to_f4(*(const unsigned*)(base + (size_t)s2 * 128));
            float4 f3 = fp8x4_to_f4(*(const unsigned*)(base + (size_t)s3 * 128));
            a0 += (f0.x + f1.x) + (f2.x + f3.x);
            a1 += (f0.y + f1.y) + (f2.y + f3.y);
            a2 += (f0.z + f1.z) + (f2.z + f3.z);
            a3 += (f0.w + f1.w) + (f2.w + f3.w);
        }
        for (; jj + 2 <= rem; jj += 2) {
            int s = __shfl(cj, jj + half, 64);
            float4 f = fp8x4_to_f4(*(const unsigned*)(base + (size_t)s * 128));
            a0 += f.x; a1 += f.y; a2 += f.z; a3 += f.w;
        }
        if (jj < rem) {
            int s = __shfl(cj, jj, 64);
            float4 f = fp8x4_to_f4(*(const unsigned*)(base + (size_t)s * 128));
            if (half == 0) { a0 += f.x; a1 += f.y; a2 += f.z; a3 += f.w; }
        }
    }
    a0 += __shfl_xor(a0, 32, 64);
    a1 += __shfl_xor(a1, 32, 64);
    a2 += __shfl_xor(a2, 32, 64);
    a3 += __shfl_xor(a3, 32, 64);
    if (half == 0) {
        float4 fv = fp8x4_to_f4(*(const unsigned*)(base + (size_t)v * 128));
        float4 bb = *(const float4*)(bias + lane32 * 4);
        bf16x4 o;
        o[0] = (bf16)(di * (a0 + fv.x) + bb.x);
        o[1] = (bf16)(di * (a1 + fv.y) + bb.y);
        o[2] = (bf16)(di * (a2 + fv.z) + bb.z);
        o[3] = (bf16)(di * (a3 + fv.w) + bb.w);
        *(bf16x4*)(out + (size_t)v * outStride + lane32 * 4) = o;
    }
}

// ---------------- softmax final ----------------
__launch_bounds__(256)
__global__ void softmax_final(const float* __restrict__ part, const float* __restrict__ lb2,
                              float* __restrict__ out, int n) {
    int i = blockIdx.x * 256 + threadIdx.x;
    if (i >= n) return;
    size_t seg = (size_t)n * 2;
    float2 p0 = *(const float2*)(part + (size_t)i * 2);
    float2 p1 = *(const float2*)(part + seg + (size_t)i * 2);
    float2 p2 = *(const float2*)(part + 2 * seg + (size_t)i * 2);
    float l0 = p0.x + p1.x + p2.x + lb2[0];
    float l1 = p0.y + p1.y + p2.y + lb2[1];
    *(float2*)(out + (size_t)i * 2) = make_float2(l0, l1);
    float m  = fmaxf(l0, l1);
    float e0 = expf(l0 - m), e1 = expf(l1 - m);
    float inv = 1.f / (e0 + e1);
    *(float2*)(out + seg + (size_t)i * 2) = make_float2(e0 * inv, e1 * inv);
}

extern "C" void kernel_launch(void* const* d_in, const int* in_sizes, int n_in,
                              void* d_out, int out_size, void* d_ws, size_t ws_size,
                              hipStream_t stream) {
    const float* x   = (const float*)d_in[0];
    const int*   ei  = (const int*)d_in[1];
    const float* W1  = (const float*)d_in[2];
    const float* b1  = (const float*)d_in[3];
    const float* W2  = (const float*)d_in[4];
    const float* b2  = (const float*)d_in[5];
    const float* W3  = (const float*)d_in[6];
    const float* b3  = (const float*)d_in[7];
    const float* lW1 = (const float*)d_in[8];
    const float* lb1 = (const float*)d_in[9];
    const float* lW2 = (const float*)d_in[10];
    const float* lb2 = (const float*)d_in[11];
    float* out = (float*)d_out;

    int N = in_sizes[0] / 64;
    int E = in_sizes[1] / 2;
    const int* src = ei;
    const int* dst = ei + E;

    char* ws = (char*)d_ws;
    size_t off = 0;
    auto take = [&](size_t bytes) -> char* {
        char* p = ws + off;
        off += (bytes + 255) & ~(size_t)255;
        return p;
    };
    int nBlk  = (N + 255) / 256;
    int nbuck = nBlk;
    int*   cnt    = (int*)take((size_t)N * 4);         // fallback only
    int*   fill   = (int*)take((size_t)N * 4);         // fallback only
    int*   rpS    = (int*)take((size_t)N * 4);
    int*   rpE    = (int*)take((size_t)N * 4);
    float* dinv   = (float*)take((size_t)N * 4);
    int*   bsum   = (int*)take((size_t)nBlk * 4);      // fallback only
    int*   gcount = (int*)take((size_t)nbuck * 4);
    size_t regionE = (nbuck <= 256 && N <= 65536)
                   ? (size_t)nbuck * BUCKET_CAP : (size_t)E;
    int*   col    = (int*)take(regionE * 4);
    unsigned int* pairs = (unsigned int*)take(regionE * 4);
    bf16*  xs0    = (bf16*)take((size_t)N * 64 * 2);
    bf16*  ax     = (bf16*)take((size_t)N * 64 * 2);
    bf16*  Wt1    = (bf16*)take((size_t)64 * 128 * 2);
    bf16*  Wt2    = (bf16*)take((size_t)128 * 128 * 2);
    bf16*  Wt3    = (bf16*)take((size_t)128 * 128 * 2);
    bf16*  lW1_bf = (bf16*)take((size_t)384 * 384 * 2);
    fp8s*  xw8    = (fp8s*)take((size_t)N * 128);
    bf16*  hcat   = (bf16*)take((size_t)N * 384 * 2);
    float* part   = (float*)take((size_t)N * 2 * 3 * 4);

    // CSR build + prep (3 dispatches: memset + bin_prep(+weights) + fill)
    if (nbuck <= 256 && N <= 65536) {
        hipMemsetAsync(gcount, 0, (size_t)nbuck * 4, stream);
        bin_prep<<<nbuck + 736, 256, 0, stream>>>(
            src, dst, gcount, pairs, E, nbuck,
            W1, W2, W3, lW1, Wt1, Wt2, Wt3, lW1_bf);
        csr_fill_full<<<nbuck, 256, 0, stream>>>(
            pairs, gcount, x, rpS, rpE, dinv, col, xs0, N);
    } else {
        bin_prep<<<736, 256, 0, stream>>>(                 // weights only
            src, dst, gcount, pairs, 0, 0,
            W1, W2, W3, lW1, Wt1, Wt2, Wt3, lW1_bf);
        init_kernel<<<nBlk, 256, 0, stream>>>(cnt, fill, N);
        hist_kernel<<<(E + 255) / 256, 256, 0, stream>>>(dst, cnt, E);
        block_reduce<<<nBlk, 256, 0, stream>>>(cnt, bsum, N);
        scan_bsums<<<1, 256, 0, stream>>>(bsum, nBlk);
        write_rp_fb<<<nBlk, 256, 0, stream>>>(cnt, bsum, x, rpS, rpE, dinv, xs0, N);
        fill_kernel<<<(E + 255) / 256, 256, 0, stream>>>(src, dst, rpS, fill, col, E);
    }

    int gemmBlocks = (N + 127) / 128;
    int aggBlocks  = (N + 3) / 4;

    // conv1: aggregate first (64-dim bf16 pair-gather), then GEMM (+b1)
    aggregate64<<<aggBlocks, 256, 0, stream>>>(xs0, rpS, rpE, col, dinv, ax, N);
    mfma_gemm<1, bf16><<<dim3(gemmBlocks, 1), 256, 0, stream>>>(
        ax, 64, 64, Wt1, b1, nullptr, hcat + 0, 384, N);
    // conv2: GEMM -> fp8 xw (rows pre-scaled by dinv), aggregate fp8 (+bias)
    mfma_gemm<0, fp8s><<<dim3(gemmBlocks, 1), 256, 0, stream>>>(
        hcat + 0, 384, 128, Wt2, nullptr, dinv, xw8, 128, N);
    aggregate_fp8<<<aggBlocks, 256, 0, stream>>>(xw8, rpS, rpE, col, dinv, b2, hcat + 128, 384, N);
    // conv3
    mfma_gemm<0, fp8s><<<dim3(gemmBlocks, 1), 256, 0, stream>>>(
        hcat + 128, 384, 128, Wt3, nullptr, dinv, xw8, 128, N);
    aggregate_fp8<<<aggBlocks, 256, 0, stream>>>(xw8, rpS, rpE, col, dinv, b3, hcat + 256, 384, N);

    // MLP head: linear1+relu+linear2 fused (partial logits per y), then softmax
    mfma_gemm<3, bf16><<<dim3(gemmBlocks, 3), 256, 0, stream>>>(
        hcat, 384, 384, lW1_bf, lb1, nullptr, (bf16*)nullptr, 0, N, lW2, part);
    softmax_final<<<(N + 255) / 256, 256, 0, stream>>>(part, lb2, out, N);
}